// Round 1
// baseline (346.158 us; speedup 1.0000x reference)
//
#include <hip/hip_runtime.h>

typedef __bf16 bf16x8 __attribute__((ext_vector_type(8)));
typedef float f32x4 __attribute__((ext_vector_type(4)));
typedef unsigned short u16x8 __attribute__((ext_vector_type(8)));

// ---------- helpers ----------

__device__ __forceinline__ unsigned short f2bf(float f) {
  unsigned u = __builtin_bit_cast(unsigned, f);
  u = (u + 0x7FFFu + ((u >> 16) & 1u)) >> 16;   // RNE
  return (unsigned short)u;
}

__device__ __forceinline__ void load_lds16(const void* g, void* l) {
  __builtin_amdgcn_global_load_lds(
      (__attribute__((address_space(1))) void*)g,
      (__attribute__((address_space(3))) void*)l, 16, 0, 0);
}

// ---------- stage 0: dtype convert ----------
// x: 4M elems (1M float4 groups); each W: 1M elems (256K groups). total 2M groups.
__global__ __launch_bounds__(256) void k_convert(
    const float* __restrict__ x,
    const float* __restrict__ wq, const float* __restrict__ wk,
    const float* __restrict__ wv, const float* __restrict__ wo,
    unsigned short* __restrict__ xb,
    unsigned short* __restrict__ wqb, unsigned short* __restrict__ wkb,
    unsigned short* __restrict__ wvb, unsigned short* __restrict__ wob) {
  const int g = blockIdx.x * 256 + threadIdx.x;  // exactly 2M threads
  const float* src;
  unsigned short* dst;
  int off;
  if (g < (1 << 20)) {
    src = x; dst = xb; off = g;
  } else {
    const int q = g - (1 << 20);
    const int t = q >> 18;
    off = q & ((1 << 18) - 1);
    src = (t == 0) ? wq : (t == 1) ? wk : (t == 2) ? wv : wo;
    dst = (t == 0) ? wqb : (t == 1) ? wkb : (t == 2) ? wvb : wob;
  }
  const float4 v = ((const float4*)src)[off];
  ushort4 r;
  r.x = f2bf(v.x); r.y = f2bf(v.y); r.z = f2bf(v.z); r.w = f2bf(v.w);
  ((ushort4*)dst)[off] = r;
}

// ---------- stage 0b: rope table ----------
__global__ __launch_bounds__(256) void k_rope_tab(const int* __restrict__ tpos,
                                                  float* __restrict__ ct,
                                                  float* __restrict__ st) {
  const int idx = blockIdx.x * 256 + threadIdx.x;  // 2048*32 = 64K
  const int s = idx >> 5, i = idx & 31;
  const double p = (double)tpos[s];
  const double f = p * pow(10000.0, -(double)(2 * i) / 64.0);
  ct[idx] = (float)cos(f);
  st[idx] = (float)sin(f);
}

// ---------- GEMM core: C[128x128] += A[128xK] * B[128xK]^T, K=1024, BK=32 ----------
// A,B bf16 row-major with row stride 1024. 256 threads = 4 waves (2x2 of 64x64).
__device__ __forceinline__ void gemm_core_1024(
    const unsigned short* __restrict__ Ag,  // at row bm
    const unsigned short* __restrict__ Bg,  // at row bn
    unsigned short* As, unsigned short* Bs, f32x4 (&acc)[4][4], int tid) {
  const int lane = tid & 63;
  const int w = tid >> 6;
  const int wm = (w >> 1) * 64;
  const int wn = (w & 1) * 64;
  const int lr = lane & 15;
  const int lg8 = (lane >> 4) * 8;
  const int c0 = tid, c1 = 256 + tid;
  const int ar0 = c0 >> 2, ac0 = (c0 & 3) * 8;
  const int ar1 = c1 >> 2, ac1 = (c1 & 3) * 8;

  for (int kt = 0; kt < 1024; kt += 32) {
    // stage 128x32 A-tile and B-tile (8KB each) via direct-to-LDS 16B copies
    load_lds16(Ag + ar0 * 1024 + kt + ac0, As + c0 * 8);
    load_lds16(Ag + ar1 * 1024 + kt + ac1, As + c1 * 8);
    load_lds16(Bg + ar0 * 1024 + kt + ac0, Bs + c0 * 8);
    load_lds16(Bg + ar1 * 1024 + kt + ac1, Bs + c1 * 8);
    __syncthreads();
    bf16x8 af[4], bfv[4];
#pragma unroll
    for (int mi = 0; mi < 4; ++mi)
      af[mi] = *(const bf16x8*)(As + (wm + mi * 16 + lr) * 32 + lg8);
#pragma unroll
    for (int ni = 0; ni < 4; ++ni)
      bfv[ni] = *(const bf16x8*)(Bs + (wn + ni * 16 + lr) * 32 + lg8);
#pragma unroll
    for (int mi = 0; mi < 4; ++mi)
#pragma unroll
      for (int ni = 0; ni < 4; ++ni)
        acc[mi][ni] = __builtin_amdgcn_mfma_f32_16x16x32_bf16(
            af[mi], bfv[ni], acc[mi][ni], 0, 0, 0);
    __syncthreads();
  }
}

// ---------- stage 1: q/k/v projection + rope, write bf16 [B*H][S][64] ----------
__global__ __launch_bounds__(256) void k_proj(
    const unsigned short* __restrict__ Xb,
    const unsigned short* __restrict__ Wq, const unsigned short* __restrict__ Wk,
    const unsigned short* __restrict__ Wv,
    const float* __restrict__ ctab, const float* __restrict__ stab,
    unsigned short* __restrict__ Qo, unsigned short* __restrict__ Ko,
    unsigned short* __restrict__ Vo) {
  __shared__ __align__(16) unsigned short As[128 * 32];
  __shared__ __align__(16) unsigned short Bs[128 * 32];
  const int z = blockIdx.z;
  const unsigned short* Wsel = (z == 0) ? Wq : (z == 1) ? Wk : Wv;
  unsigned short* Out = (z == 0) ? Qo : (z == 1) ? Ko : Vo;
  const int tid = threadIdx.x;
  const int bm = blockIdx.x * 128, bn = blockIdx.y * 128;
  f32x4 acc[4][4] = {};
  gemm_core_1024(Xb + (size_t)bm * 1024, Wsel + (size_t)bn * 1024, As, Bs, acc, tid);

  const int lane = tid & 63, w = tid >> 6;
  const int wm = (w >> 1) * 64, wn = (w & 1) * 64;
  const int lr = lane & 15, lg = lane >> 4;
  const bool rope = (z < 2);
  const bool odd = lane & 1;
#pragma unroll
  for (int mi = 0; mi < 4; ++mi) {
#pragma unroll
    for (int ni = 0; ni < 4; ++ni) {
#pragma unroll
      for (int reg = 0; reg < 4; ++reg) {
        const int r = bm + wm + mi * 16 + lg * 4 + reg;  // D row
        const int e = bn + wn + ni * 16 + lr;            // D col
        float val = acc[mi][ni][reg];
        const float partner = __shfl_xor(val, 1);  // other half of rope pair
        const int s = r & 2047, b = r >> 11;
        const int h = e >> 6, d = e & 63;
        float outv = val;
        if (rope) {
          const int i = d >> 1;
          const float c = ctab[s * 32 + i];
          const float sn = stab[s * 32 + i];
          outv = odd ? (val * c + partner * sn) : (val * c - partner * sn);
        }
        Out[((size_t)(b * 16 + h) * 2048 + s) * 64 + d] = f2bf(outv);
      }
    }
  }
}

// ---------- stage 2: causal flash attention ----------
// grid (32 q-tiles of 64, 32 bh). 4 waves/block, each owns 16 q rows.
__global__ __launch_bounds__(256) void k_attn(
    const unsigned short* __restrict__ Q, const unsigned short* __restrict__ K,
    const unsigned short* __restrict__ V, unsigned short* __restrict__ O) {
  __shared__ __align__(16) unsigned short Ks[32 * 64];
  __shared__ __align__(16) unsigned short Vts[64 * 32];  // transposed [dv][kv]
  __shared__ __align__(16) unsigned short Pl[4][16 * 32];
  const int bh = blockIdx.y;
  const int qb = blockIdx.x * 64;
  const int tid = threadIdx.x, lane = tid & 63, w = tid >> 6;
  const int lr = lane & 15, lg = lane >> 4;
  const unsigned short* Qg = Q + (size_t)bh * 2048 * 64;
  const unsigned short* Kg = K + (size_t)bh * 2048 * 64;
  const unsigned short* Vg = V + (size_t)bh * 2048 * 64;
  const int qrow = qb + w * 16;

  const bf16x8 qf0 = *(const bf16x8*)(Qg + (qrow + lr) * 64 + lg * 8);
  const bf16x8 qf1 = *(const bf16x8*)(Qg + (qrow + lr) * 64 + 32 + lg * 8);

  f32x4 oacc[4] = {};
  float mrow[4], lrow[4];
#pragma unroll
  for (int i = 0; i < 4; ++i) { mrow[i] = -__builtin_inff(); lrow[i] = 0.f; }

  const int vrow = tid >> 3;        // 0..31 (kv within tile)
  const int vcol = (tid & 7) * 8;   // 0..56 (d)
  const int T = qb / 32 + 2;
  for (int t = 0; t < T; ++t) {
    const int kv0 = t * 32;
    __syncthreads();  // previous iteration's LDS reads done
    load_lds16(Kg + (kv0 + vrow) * 64 + vcol, Ks + tid * 8);
    const u16x8 vv = *(const u16x8*)(Vg + (kv0 + vrow) * 64 + vcol);
#pragma unroll
    for (int j = 0; j < 8; ++j) Vts[(vcol + j) * 32 + vrow] = vv[j];
    __syncthreads();

    // S = Q K^T for this wave's 16 rows x 32 kv
    f32x4 sacc[2];
#pragma unroll
    for (int nt = 0; nt < 2; ++nt) {
      const bf16x8 kb0 = *(const bf16x8*)(Ks + (nt * 16 + lr) * 64 + lg * 8);
      const bf16x8 kb1 = *(const bf16x8*)(Ks + (nt * 16 + lr) * 64 + 32 + lg * 8);
      const f32x4 zero = {0.f, 0.f, 0.f, 0.f};
      sacc[nt] = __builtin_amdgcn_mfma_f32_16x16x32_bf16(qf0, kb0, zero, 0, 0, 0);
      sacc[nt] = __builtin_amdgcn_mfma_f32_16x16x32_bf16(qf1, kb1, sacc[nt], 0, 0, 0);
    }
    // scale + causal mask + row max
    float pm[4] = {-__builtin_inff(), -__builtin_inff(), -__builtin_inff(), -__builtin_inff()};
#pragma unroll
    for (int nt = 0; nt < 2; ++nt)
#pragma unroll
      for (int reg = 0; reg < 4; ++reg) {
        float sv = sacc[nt][reg] * 0.125f;
        const int kg = kv0 + nt * 16 + lr;
        const int qg = qrow + lg * 4 + reg;
        if (kg > qg) sv = -__builtin_inff();
        sacc[nt][reg] = sv;
        pm[reg] = fmaxf(pm[reg], sv);
      }
#pragma unroll
    for (int off = 1; off < 16; off <<= 1)
#pragma unroll
      for (int reg = 0; reg < 4; ++reg)
        pm[reg] = fmaxf(pm[reg], __shfl_xor(pm[reg], off));

    float rs[4];
#pragma unroll
    for (int reg = 0; reg < 4; ++reg) {
      const float mn = fmaxf(mrow[reg], pm[reg]);
      const float al = expf(mrow[reg] - mn);
      mrow[reg] = mn;
      lrow[reg] *= al;
      const float p0 = expf(sacc[0][reg] - mn);
      const float p1 = expf(sacc[1][reg] - mn);
      sacc[0][reg] = p0;
      sacc[1][reg] = p1;
      rs[reg] = p0 + p1;
#pragma unroll
      for (int nt = 0; nt < 4; ++nt) oacc[nt][reg] *= al;
    }
#pragma unroll
    for (int off = 1; off < 16; off <<= 1)
#pragma unroll
      for (int reg = 0; reg < 4; ++reg) rs[reg] += __shfl_xor(rs[reg], off);
#pragma unroll
    for (int reg = 0; reg < 4; ++reg) lrow[reg] += rs[reg];

    // P through per-wave LDS to re-layout for PV A-fragment (wave-local, no barrier)
    unsigned short* Pw = Pl[w];
#pragma unroll
    for (int nt = 0; nt < 2; ++nt)
#pragma unroll
      for (int reg = 0; reg < 4; ++reg)
        Pw[(lg * 4 + reg) * 32 + nt * 16 + lr] = f2bf(sacc[nt][reg]);
    const bf16x8 pa = *(const bf16x8*)(Pw + lr * 32 + lg * 8);
#pragma unroll
    for (int nt = 0; nt < 4; ++nt) {
      const bf16x8 vb = *(const bf16x8*)(Vts + (nt * 16 + lr) * 32 + lg * 8);
      oacc[nt] = __builtin_amdgcn_mfma_f32_16x16x32_bf16(pa, vb, oacc[nt], 0, 0, 0);
    }
  }

  // normalize + write attn out as bf16 [B][S][H*64]
  const int b = bh >> 4, h = bh & 15;
#pragma unroll
  for (int reg = 0; reg < 4; ++reg) {
    const float inv = 1.0f / lrow[reg];
    const int s = qrow + lg * 4 + reg;
#pragma unroll
    for (int nt = 0; nt < 4; ++nt) {
      const int dv = nt * 16 + lr;
      O[((size_t)b * 2048 + s) * 1024 + h * 64 + dv] = f2bf(oacc[nt][reg] * inv);
    }
  }
}

// ---------- stage 3: output projection, f32 epilogue ----------
__global__ __launch_bounds__(256) void k_out(const unsigned short* __restrict__ Ab,
                                             const unsigned short* __restrict__ Wo,
                                             float* __restrict__ Out) {
  __shared__ __align__(16) unsigned short As[128 * 32];
  __shared__ __align__(16) unsigned short Bs[128 * 32];
  const int tid = threadIdx.x;
  const int bm = blockIdx.x * 128, bn = blockIdx.y * 128;
  f32x4 acc[4][4] = {};
  gemm_core_1024(Ab + (size_t)bm * 1024, Wo + (size_t)bn * 1024, As, Bs, acc, tid);
  const int lane = tid & 63, w = tid >> 6;
  const int wm = (w >> 1) * 64, wn = (w & 1) * 64;
  const int lr = lane & 15, lg = lane >> 4;
#pragma unroll
  for (int mi = 0; mi < 4; ++mi)
#pragma unroll
    for (int ni = 0; ni < 4; ++ni)
#pragma unroll
      for (int reg = 0; reg < 4; ++reg) {
        const int r = bm + wm + mi * 16 + lg * 4 + reg;
        const int e = bn + wn + ni * 16 + lr;
        Out[(size_t)r * 1024 + e] = acc[mi][ni][reg];
      }
}

// ---------- launch ----------
extern "C" void kernel_launch(void* const* d_in, const int* in_sizes, int n_in,
                              void* d_out, int out_size, void* d_ws, size_t ws_size,
                              hipStream_t stream) {
  const float* x = (const float*)d_in[0];
  const float* Wq = (const float*)d_in[1];
  const float* Wk = (const float*)d_in[2];
  const float* Wv = (const float*)d_in[3];
  const float* Wo = (const float*)d_in[4];
  const int* tpos = (const int*)d_in[5];
  float* out = (float*)d_out;
  char* ws = (char*)d_ws;
  const size_t MB = 1024 * 1024;
  unsigned short* xb = (unsigned short*)(ws);             // 8 MB
  unsigned short* wqb = (unsigned short*)(ws + 8 * MB);   // 2 MB
  unsigned short* wkb = (unsigned short*)(ws + 10 * MB);
  unsigned short* wvb = (unsigned short*)(ws + 12 * MB);
  unsigned short* wob = (unsigned short*)(ws + 14 * MB);
  unsigned short* Qb = (unsigned short*)(ws + 16 * MB);   // 8 MB each
  unsigned short* Kb = (unsigned short*)(ws + 24 * MB);
  unsigned short* Vb = (unsigned short*)(ws + 32 * MB);
  unsigned short* Ab = (unsigned short*)(ws + 40 * MB);
  float* ctab = (float*)(ws + 48 * MB);                   // 256 KB
  float* stab = (float*)(ws + 48 * MB + 256 * 1024);

  k_convert<<<dim3(8192), dim3(256), 0, stream>>>(x, Wq, Wk, Wv, Wo, xb, wqb, wkb,
                                                  wvb, wob);
  k_rope_tab<<<dim3(256), dim3(256), 0, stream>>>(tpos, ctab, stab);
  k_proj<<<dim3(32, 8, 3), dim3(256), 0, stream>>>(xb, wqb, wkb, wvb, ctab, stab,
                                                   Qb, Kb, Vb);
  k_attn<<<dim3(32, 32), dim3(256), 0, stream>>>(Qb, Kb, Vb, Ab);
  k_out<<<dim3(32, 8), dim3(256), 0, stream>>>(Ab, wob, out);
}

// Round 2
// 262.502 us; speedup vs baseline: 1.3187x; 1.3187x over previous
//
#include <hip/hip_runtime.h>

typedef __bf16 bf16x8 __attribute__((ext_vector_type(8)));
typedef float f32x4 __attribute__((ext_vector_type(4)));
typedef unsigned short u16x8 __attribute__((ext_vector_type(8)));

// ---------- helpers ----------

__device__ __forceinline__ unsigned short f2bf(float f) {
  unsigned u = __builtin_bit_cast(unsigned, f);
  u = (u + 0x7FFFu + ((u >> 16) & 1u)) >> 16;   // RNE
  return (unsigned short)u;
}

__device__ __forceinline__ void load_lds16(const void* g, void* l) {
  __builtin_amdgcn_global_load_lds(
      (__attribute__((address_space(1))) void*)g,
      (__attribute__((address_space(3))) void*)l, 16, 0, 0);
}

// ---------- stage 0: dtype convert ----------
__global__ __launch_bounds__(256) void k_convert(
    const float* __restrict__ x,
    const float* __restrict__ wq, const float* __restrict__ wk,
    const float* __restrict__ wv, const float* __restrict__ wo,
    unsigned short* __restrict__ xb,
    unsigned short* __restrict__ wqb, unsigned short* __restrict__ wkb,
    unsigned short* __restrict__ wvb, unsigned short* __restrict__ wob) {
  const int g = blockIdx.x * 256 + threadIdx.x;  // exactly 2M threads
  const float* src;
  unsigned short* dst;
  int off;
  if (g < (1 << 20)) {
    src = x; dst = xb; off = g;
  } else {
    const int q = g - (1 << 20);
    const int t = q >> 18;
    off = q & ((1 << 18) - 1);
    src = (t == 0) ? wq : (t == 1) ? wk : (t == 2) ? wv : wo;
    dst = (t == 0) ? wqb : (t == 1) ? wkb : (t == 2) ? wvb : wob;
  }
  const float4 v = ((const float4*)src)[off];
  ushort4 r;
  r.x = f2bf(v.x); r.y = f2bf(v.y); r.z = f2bf(v.z); r.w = f2bf(v.w);
  ((ushort4*)dst)[off] = r;
}

// ---------- stage 0b: rope table ----------
__global__ __launch_bounds__(256) void k_rope_tab(const int* __restrict__ tpos,
                                                  float* __restrict__ ct,
                                                  float* __restrict__ st) {
  const int idx = blockIdx.x * 256 + threadIdx.x;  // 2048*32 = 64K
  const int s = idx >> 5, i = idx & 31;
  const double p = (double)tpos[s];
  const double f = p * pow(10000.0, -(double)(2 * i) / 64.0);
  ct[idx] = (float)cos(f);
  st[idx] = (float)sin(f);
}

// ---------- GEMM core: C[128x128] += A[128xK] * B[128xK]^T, K=1024, BK=32 ----------
__device__ __forceinline__ void gemm_core_1024(
    const unsigned short* __restrict__ Ag,  // at row bm
    const unsigned short* __restrict__ Bg,  // at row bn
    unsigned short* As, unsigned short* Bs, f32x4 (&acc)[4][4], int tid) {
  const int lane = tid & 63;
  const int w = tid >> 6;
  const int wm = (w >> 1) * 64;
  const int wn = (w & 1) * 64;
  const int lr = lane & 15;
  const int lg8 = (lane >> 4) * 8;
  const int c0 = tid, c1 = 256 + tid;
  const int ar0 = c0 >> 2, ac0 = (c0 & 3) * 8;
  const int ar1 = c1 >> 2, ac1 = (c1 & 3) * 8;

  for (int kt = 0; kt < 1024; kt += 32) {
    load_lds16(Ag + ar0 * 1024 + kt + ac0, As + c0 * 8);
    load_lds16(Ag + ar1 * 1024 + kt + ac1, As + c1 * 8);
    load_lds16(Bg + ar0 * 1024 + kt + ac0, Bs + c0 * 8);
    load_lds16(Bg + ar1 * 1024 + kt + ac1, Bs + c1 * 8);
    __syncthreads();
    bf16x8 af[4], bfv[4];
#pragma unroll
    for (int mi = 0; mi < 4; ++mi)
      af[mi] = *(const bf16x8*)(As + (wm + mi * 16 + lr) * 32 + lg8);
#pragma unroll
    for (int ni = 0; ni < 4; ++ni)
      bfv[ni] = *(const bf16x8*)(Bs + (wn + ni * 16 + lr) * 32 + lg8);
#pragma unroll
    for (int mi = 0; mi < 4; ++mi)
#pragma unroll
      for (int ni = 0; ni < 4; ++ni)
        acc[mi][ni] = __builtin_amdgcn_mfma_f32_16x16x32_bf16(
            af[mi], bfv[ni], acc[mi][ni], 0, 0, 0);
    __syncthreads();
  }
}

// ---------- stage 1: q/k/v projection + rope ----------
// Q,K out: bf16 [B*H][S][64]. V out: TRANSPOSED bf16 [B*H][64][S] (for attn staging).
__global__ __launch_bounds__(256) void k_proj(
    const unsigned short* __restrict__ Xb,
    const unsigned short* __restrict__ Wq, const unsigned short* __restrict__ Wk,
    const unsigned short* __restrict__ Wv,
    const float* __restrict__ ctab, const float* __restrict__ stab,
    unsigned short* __restrict__ Qo, unsigned short* __restrict__ Ko,
    unsigned short* __restrict__ Vo) {
  __shared__ __align__(16) unsigned short As[128 * 32];
  __shared__ __align__(16) unsigned short Bs[128 * 32];
  const int z = blockIdx.z;
  const unsigned short* Wsel = (z == 0) ? Wq : (z == 1) ? Wk : Wv;
  unsigned short* Out = (z == 0) ? Qo : (z == 1) ? Ko : Vo;
  const int tid = threadIdx.x;
  const int bm = blockIdx.x * 128, bn = blockIdx.y * 128;
  f32x4 acc[4][4] = {};
  gemm_core_1024(Xb + (size_t)bm * 1024, Wsel + (size_t)bn * 1024, As, Bs, acc, tid);

  const int lane = tid & 63, w = tid >> 6;
  const int wm = (w >> 1) * 64, wn = (w & 1) * 64;
  const int lr = lane & 15, lg = lane >> 4;
  const bool rope = (z < 2);
  const bool odd = lane & 1;
#pragma unroll
  for (int mi = 0; mi < 4; ++mi) {
#pragma unroll
    for (int ni = 0; ni < 4; ++ni) {
#pragma unroll
      for (int reg = 0; reg < 4; ++reg) {
        const int r = bm + wm + mi * 16 + lg * 4 + reg;  // D row -> (b,s)
        const int e = bn + wn + ni * 16 + lr;            // D col -> (h,d)
        float val = acc[mi][ni][reg];
        const float partner = __shfl_xor(val, 1);
        const int s = r & 2047, b = r >> 11;
        const int h = e >> 6, d = e & 63;
        float outv = val;
        if (rope) {
          const int i = d >> 1;
          const float c = ctab[s * 32 + i];
          const float sn = stab[s * 32 + i];
          outv = odd ? (val * c + partner * sn) : (val * c - partner * sn);
        }
        if (z == 2)
          Out[((size_t)(b * 16 + h) * 64 + d) * 2048 + s] = f2bf(outv);
        else
          Out[((size_t)(b * 16 + h) * 2048 + s) * 64 + d] = f2bf(outv);
      }
    }
  }
}

// ---------- stage 2: causal flash attention ----------
// grid (16 q-tiles of 128 [reversed], 32 bh). 4 waves, each owns 32 q rows. KV tile 64.
__global__ __launch_bounds__(256) void k_attn(
    const unsigned short* __restrict__ Q, const unsigned short* __restrict__ K,
    const unsigned short* __restrict__ Vt, unsigned short* __restrict__ O) {
  __shared__ __align__(16) unsigned short Ks[64 * 64];   // swizzled [kv][d]
  __shared__ __align__(16) unsigned short Vs[64 * 64];   // swizzled [dv][kv]
  __shared__ __align__(16) unsigned short Pl[4][32 * 68];
  const int bh = blockIdx.y;
  const int qt = gridDim.x - 1 - blockIdx.x;  // heavy blocks first
  const int qb = qt * 128;
  const int tid = threadIdx.x, lane = tid & 63, w = tid >> 6;
  const int lr = lane & 15, lg = lane >> 4;
  const unsigned short* Qg = Q + (size_t)bh * 2048 * 64;
  const unsigned short* Kg = K + (size_t)bh * 2048 * 64;
  const unsigned short* Vg = Vt + (size_t)bh * 64 * 2048;
  const int qrow = qb + w * 32;

  // Q fragments: 32 rows x 64 d per wave
  bf16x8 qf[2][2];
#pragma unroll
  for (int mi = 0; mi < 2; ++mi)
#pragma unroll
    for (int h = 0; h < 2; ++h)
      qf[mi][h] = *(const bf16x8*)(Qg + (qrow + mi * 16 + lr) * 64 + h * 32 + lg * 8);

  f32x4 oacc[2][4] = {};
  float mrow[2][4], lrow[2][4];
#pragma unroll
  for (int mi = 0; mi < 2; ++mi)
#pragma unroll
    for (int r = 0; r < 4; ++r) { mrow[mi][r] = -__builtin_inff(); lrow[mi][r] = 0.f; }

  // staging: 512 chunks of 16B per tile buffer; thread does chunks tid and tid+256.
  // chunk c -> row r=c>>3, slot j=c&7; source col-chunk = j ^ (r&7)  (XOR swizzle)
  const int r0 = tid >> 3, j0 = tid & 7, cs0 = j0 ^ (r0 & 7);
  const int r1 = r0 + 32, cs1 = j0 ^ (r1 & 7);

  const float SCL = 0.125f * 1.44269504088896f;  // 1/sqrt(64) * log2(e)
  const int T = qt * 2 + 2;
  for (int t = 0; t < T; ++t) {
    const int kv0 = t * 64;
    __syncthreads();  // previous tile's LDS reads done
    load_lds16(Kg + (size_t)(kv0 + r0) * 64 + cs0 * 8, Ks + tid * 8);
    load_lds16(Kg + (size_t)(kv0 + r1) * 64 + cs1 * 8, Ks + (tid + 256) * 8);
    load_lds16(Vg + (size_t)r0 * 2048 + kv0 + cs0 * 8, Vs + tid * 8);
    load_lds16(Vg + (size_t)r1 * 2048 + kv0 + cs1 * 8, Vs + (tid + 256) * 8);
    __syncthreads();

    if (kv0 >= qrow + 32) continue;  // wave-uniform: fully masked tile

    // ---- S = Q K^T : 32 q x 64 kv ----
    f32x4 sacc[2][4];
#pragma unroll
    for (int nt = 0; nt < 4; ++nt) {
      const int row = nt * 16 + lr;
      const bf16x8 kb0 = *(const bf16x8*)(Ks + row * 64 + ((lg ^ (row & 7)) * 8));
      const bf16x8 kb1 = *(const bf16x8*)(Ks + row * 64 + (((lg + 4) ^ (row & 7)) * 8));
#pragma unroll
      for (int mi = 0; mi < 2; ++mi) {
        f32x4 z = {0.f, 0.f, 0.f, 0.f};
        z = __builtin_amdgcn_mfma_f32_16x16x32_bf16(qf[mi][0], kb0, z, 0, 0, 0);
        sacc[mi][nt] = __builtin_amdgcn_mfma_f32_16x16x32_bf16(qf[mi][1], kb1, z, 0, 0, 0);
      }
    }

    // ---- scale (+mask) + row max ----
    const bool needmask = (kv0 + 63 > qrow);  // wave-uniform
    float pm[2][4];
#pragma unroll
    for (int mi = 0; mi < 2; ++mi)
#pragma unroll
      for (int r = 0; r < 4; ++r) pm[mi][r] = -__builtin_inff();
#pragma unroll
    for (int mi = 0; mi < 2; ++mi)
#pragma unroll
      for (int nt = 0; nt < 4; ++nt)
#pragma unroll
        for (int reg = 0; reg < 4; ++reg) {
          float sv = sacc[mi][nt][reg] * SCL;
          if (needmask) {
            const int kg = kv0 + nt * 16 + lr;
            const int qg = qrow + mi * 16 + lg * 4 + reg;
            if (kg > qg) sv = -__builtin_inff();
          }
          sacc[mi][nt][reg] = sv;
          pm[mi][reg] = fmaxf(pm[mi][reg], sv);
        }
#pragma unroll
    for (int off = 1; off < 16; off <<= 1)
#pragma unroll
      for (int mi = 0; mi < 2; ++mi)
#pragma unroll
        for (int reg = 0; reg < 4; ++reg)
          pm[mi][reg] = fmaxf(pm[mi][reg], __shfl_xor(pm[mi][reg], off));

    // ---- online softmax (exp2 domain) ----
    float al[2][4], rs[2][4];
#pragma unroll
    for (int mi = 0; mi < 2; ++mi)
#pragma unroll
      for (int reg = 0; reg < 4; ++reg) {
        const float mn = fmaxf(mrow[mi][reg], pm[mi][reg]);
        al[mi][reg] = exp2f(mrow[mi][reg] - mn);
        mrow[mi][reg] = mn;
        float s = 0.f;
#pragma unroll
        for (int nt = 0; nt < 4; ++nt) {
          const float p = exp2f(sacc[mi][nt][reg] - mn);
          sacc[mi][nt][reg] = p;
          s += p;
        }
        rs[mi][reg] = s;
      }
#pragma unroll
    for (int off = 1; off < 16; off <<= 1)
#pragma unroll
      for (int mi = 0; mi < 2; ++mi)
#pragma unroll
        for (int reg = 0; reg < 4; ++reg)
          rs[mi][reg] += __shfl_xor(rs[mi][reg], off);
#pragma unroll
    for (int mi = 0; mi < 2; ++mi)
#pragma unroll
      for (int reg = 0; reg < 4; ++reg) {
        lrow[mi][reg] = lrow[mi][reg] * al[mi][reg] + rs[mi][reg];
#pragma unroll
        for (int nt = 0; nt < 4; ++nt) oacc[mi][nt][reg] *= al[mi][reg];
      }

    // ---- P relayout through padded wave-local LDS (no barrier) ----
    unsigned short* Pw = Pl[w];
#pragma unroll
    for (int mi = 0; mi < 2; ++mi)
#pragma unroll
      for (int nt = 0; nt < 4; ++nt)
#pragma unroll
        for (int reg = 0; reg < 4; ++reg)
          Pw[(mi * 16 + lg * 4 + reg) * 68 + nt * 16 + lr] =
              f2bf(sacc[mi][nt][reg]);
    bf16x8 pa[2][2];
#pragma unroll
    for (int mi = 0; mi < 2; ++mi)
#pragma unroll
      for (int ks = 0; ks < 2; ++ks)
        pa[mi][ks] = *(const bf16x8*)(Pw + (mi * 16 + lr) * 68 + ks * 32 + lg * 8);

    // ---- O += P V : 32 q x 64 dv ----
#pragma unroll
    for (int nt = 0; nt < 4; ++nt) {
      const int row = nt * 16 + lr;
      const bf16x8 vb0 = *(const bf16x8*)(Vs + row * 64 + ((lg ^ (row & 7)) * 8));
      const bf16x8 vb1 = *(const bf16x8*)(Vs + row * 64 + (((lg + 4) ^ (row & 7)) * 8));
#pragma unroll
      for (int mi = 0; mi < 2; ++mi) {
        oacc[mi][nt] = __builtin_amdgcn_mfma_f32_16x16x32_bf16(pa[mi][0], vb0,
                                                               oacc[mi][nt], 0, 0, 0);
        oacc[mi][nt] = __builtin_amdgcn_mfma_f32_16x16x32_bf16(pa[mi][1], vb1,
                                                               oacc[mi][nt], 0, 0, 0);
      }
    }
  }

  // ---- normalize + write attn out as bf16 [B][S][H*64] ----
  const int b = bh >> 4, h = bh & 15;
#pragma unroll
  for (int mi = 0; mi < 2; ++mi)
#pragma unroll
    for (int reg = 0; reg < 4; ++reg) {
      const float inv = 1.0f / lrow[mi][reg];
      const int s = qrow + mi * 16 + lg * 4 + reg;
#pragma unroll
      for (int nt = 0; nt < 4; ++nt) {
        const int dv = nt * 16 + lr;
        O[((size_t)b * 2048 + s) * 1024 + h * 64 + dv] = f2bf(oacc[mi][nt][reg] * inv);
      }
    }
}

// ---------- stage 3: output projection, f32 epilogue ----------
__global__ __launch_bounds__(256) void k_out(const unsigned short* __restrict__ Ab,
                                             const unsigned short* __restrict__ Wo,
                                             float* __restrict__ Out) {
  __shared__ __align__(16) unsigned short As[128 * 32];
  __shared__ __align__(16) unsigned short Bs[128 * 32];
  const int tid = threadIdx.x;
  const int bm = blockIdx.x * 128, bn = blockIdx.y * 128;
  f32x4 acc[4][4] = {};
  gemm_core_1024(Ab + (size_t)bm * 1024, Wo + (size_t)bn * 1024, As, Bs, acc, tid);
  const int lane = tid & 63, w = tid >> 6;
  const int wm = (w >> 1) * 64, wn = (w & 1) * 64;
  const int lr = lane & 15, lg = lane >> 4;
#pragma unroll
  for (int mi = 0; mi < 4; ++mi)
#pragma unroll
    for (int ni = 0; ni < 4; ++ni)
#pragma unroll
      for (int reg = 0; reg < 4; ++reg) {
        const int r = bm + wm + mi * 16 + lg * 4 + reg;
        const int e = bn + wn + ni * 16 + lr;
        Out[(size_t)r * 1024 + e] = acc[mi][ni][reg];
      }
}

// ---------- launch ----------
extern "C" void kernel_launch(void* const* d_in, const int* in_sizes, int n_in,
                              void* d_out, int out_size, void* d_ws, size_t ws_size,
                              hipStream_t stream) {
  const float* x = (const float*)d_in[0];
  const float* Wq = (const float*)d_in[1];
  const float* Wk = (const float*)d_in[2];
  const float* Wv = (const float*)d_in[3];
  const float* Wo = (const float*)d_in[4];
  const int* tpos = (const int*)d_in[5];
  float* out = (float*)d_out;
  char* ws = (char*)d_ws;
  const size_t MB = 1024 * 1024;
  unsigned short* xb = (unsigned short*)(ws);             // 8 MB
  unsigned short* wqb = (unsigned short*)(ws + 8 * MB);   // 2 MB
  unsigned short* wkb = (unsigned short*)(ws + 10 * MB);
  unsigned short* wvb = (unsigned short*)(ws + 12 * MB);
  unsigned short* wob = (unsigned short*)(ws + 14 * MB);
  unsigned short* Qb = (unsigned short*)(ws + 16 * MB);   // 8 MB each
  unsigned short* Kb = (unsigned short*)(ws + 24 * MB);
  unsigned short* Vtb = (unsigned short*)(ws + 32 * MB);  // transposed V
  unsigned short* Ab = (unsigned short*)(ws + 40 * MB);
  float* ctab = (float*)(ws + 48 * MB);                   // 256 KB
  float* stab = (float*)(ws + 48 * MB + 256 * 1024);

  k_convert<<<dim3(8192), dim3(256), 0, stream>>>(x, Wq, Wk, Wv, Wo, xb, wqb, wkb,
                                                  wvb, wob);
  k_rope_tab<<<dim3(256), dim3(256), 0, stream>>>(tpos, ctab, stab);
  k_proj<<<dim3(32, 8, 3), dim3(256), 0, stream>>>(xb, wqb, wkb, wvb, ctab, stab,
                                                   Qb, Kb, Vtb);
  k_attn<<<dim3(16, 32), dim3(256), 0, stream>>>(Qb, Kb, Vtb, Ab);
  k_out<<<dim3(32, 8), dim3(256), 0, stream>>>(Ab, wob, out);
}

// Round 3
// 226.139 us; speedup vs baseline: 1.5307x; 1.1608x over previous
//
#include <hip/hip_runtime.h>

typedef __bf16 bf16x8 __attribute__((ext_vector_type(8)));
typedef float f32x4 __attribute__((ext_vector_type(4)));
typedef unsigned short u16x8 __attribute__((ext_vector_type(8)));

// ---------- helpers ----------

__device__ __forceinline__ unsigned short f2bf(float f) {
  unsigned u = __builtin_bit_cast(unsigned, f);
  u = (u + 0x7FFFu + ((u >> 16) & 1u)) >> 16;   // RNE
  return (unsigned short)u;
}

__device__ __forceinline__ void load_lds16(const void* g, void* l) {
  __builtin_amdgcn_global_load_lds(
      (__attribute__((address_space(1))) void*)g,
      (__attribute__((address_space(3))) void*)l, 16, 0, 0);
}

// ---------- stage 0: dtype convert ----------
__global__ __launch_bounds__(256) void k_convert(
    const float* __restrict__ x,
    const float* __restrict__ wq, const float* __restrict__ wk,
    const float* __restrict__ wv, const float* __restrict__ wo,
    unsigned short* __restrict__ xb,
    unsigned short* __restrict__ wqb, unsigned short* __restrict__ wkb,
    unsigned short* __restrict__ wvb, unsigned short* __restrict__ wob) {
  const int g = blockIdx.x * 256 + threadIdx.x;  // exactly 2M threads
  const float* src;
  unsigned short* dst;
  int off;
  if (g < (1 << 20)) {
    src = x; dst = xb; off = g;
  } else {
    const int q = g - (1 << 20);
    const int t = q >> 18;
    off = q & ((1 << 18) - 1);
    src = (t == 0) ? wq : (t == 1) ? wk : (t == 2) ? wv : wo;
    dst = (t == 0) ? wqb : (t == 1) ? wkb : (t == 2) ? wvb : wob;
  }
  const float4 v = ((const float4*)src)[off];
  ushort4 r;
  r.x = f2bf(v.x); r.y = f2bf(v.y); r.z = f2bf(v.z); r.w = f2bf(v.w);
  ((ushort4*)dst)[off] = r;
}

// ---------- stage 0b: rope table ----------
__global__ __launch_bounds__(256) void k_rope_tab(const int* __restrict__ tpos,
                                                  float* __restrict__ ct,
                                                  float* __restrict__ st) {
  const int idx = blockIdx.x * 256 + threadIdx.x;  // 2048*32 = 64K
  const int s = idx >> 5, i = idx & 31;
  const double p = (double)tpos[s];
  const double f = p * pow(10000.0, -(double)(2 * i) / 64.0);
  ct[idx] = (float)cos(f);
  st[idx] = (float)sin(f);
}

// ---------- GEMM core: C[128x128] += A[128xK] * B[128xK]^T, K=1024, BK=32 ----------
// 2-phase double-buffered staging with counted vmcnt. As/Bs are 2*128*32 elems.
__device__ __forceinline__ void gemm_core_1024(
    const unsigned short* __restrict__ Ag,  // at row bm
    const unsigned short* __restrict__ Bg,  // at row bn
    unsigned short* As, unsigned short* Bs, f32x4 (&acc)[4][4], int tid) {
  const int lane = tid & 63;
  const int w = tid >> 6;
  const int wm = (w >> 1) * 64;
  const int wn = (w & 1) * 64;
  const int lr = lane & 15;
  const int lg8 = (lane >> 4) * 8;
  const int c0 = tid, c1 = 256 + tid;
  const int ar0 = c0 >> 2, ac0 = (c0 & 3) * 8;
  const int ar1 = c1 >> 2, ac1 = (c1 & 3) * 8;

  auto stage = [&](int buf, int kt) {
    unsigned short* Ab = As + buf * 4096;
    unsigned short* Bb = Bs + buf * 4096;
    load_lds16(Ag + ar0 * 1024 + kt + ac0, Ab + c0 * 8);
    load_lds16(Ag + ar1 * 1024 + kt + ac1, Ab + c1 * 8);
    load_lds16(Bg + ar0 * 1024 + kt + ac0, Bb + c0 * 8);
    load_lds16(Bg + ar1 * 1024 + kt + ac1, Bb + c1 * 8);
  };

  stage(0, 0);
  for (int ki = 0; ki < 32; ++ki) {
    const int cur = ki & 1;
    if (ki + 1 < 32) {
      stage(cur ^ 1, (ki + 1) * 32);
      asm volatile("s_waitcnt vmcnt(4)" ::: "memory");
    } else {
      asm volatile("s_waitcnt vmcnt(0)" ::: "memory");
    }
    __builtin_amdgcn_s_barrier();
    const unsigned short* Ab = As + cur * 4096;
    const unsigned short* Bb = Bs + cur * 4096;
    bf16x8 af[4], bfv[4];
#pragma unroll
    for (int mi = 0; mi < 4; ++mi)
      af[mi] = *(const bf16x8*)(Ab + (wm + mi * 16 + lr) * 32 + lg8);
#pragma unroll
    for (int ni = 0; ni < 4; ++ni)
      bfv[ni] = *(const bf16x8*)(Bb + (wn + ni * 16 + lr) * 32 + lg8);
#pragma unroll
    for (int mi = 0; mi < 4; ++mi)
#pragma unroll
      for (int ni = 0; ni < 4; ++ni)
        acc[mi][ni] = __builtin_amdgcn_mfma_f32_16x16x32_bf16(
            af[mi], bfv[ni], acc[mi][ni], 0, 0, 0);
    __builtin_amdgcn_s_barrier();
  }
}

// ---------- stage 1: q/k/v projection + rope ----------
// Q,K out: bf16 [B*H][S][64]. V out: TRANSPOSED bf16 [B*H][64][S] (for attn staging).
__global__ __launch_bounds__(256) void k_proj(
    const unsigned short* __restrict__ Xb,
    const unsigned short* __restrict__ Wq, const unsigned short* __restrict__ Wk,
    const unsigned short* __restrict__ Wv,
    const float* __restrict__ ctab, const float* __restrict__ stab,
    unsigned short* __restrict__ Qo, unsigned short* __restrict__ Ko,
    unsigned short* __restrict__ Vo) {
  __shared__ __align__(16) unsigned short As[2 * 128 * 32];
  __shared__ __align__(16) unsigned short Bs[2 * 128 * 32];
  const int z = blockIdx.z;
  const unsigned short* Wsel = (z == 0) ? Wq : (z == 1) ? Wk : Wv;
  unsigned short* Out = (z == 0) ? Qo : (z == 1) ? Ko : Vo;
  const int tid = threadIdx.x;
  const int bm = blockIdx.x * 128, bn = blockIdx.y * 128;
  f32x4 acc[4][4] = {};
  gemm_core_1024(Xb + (size_t)bm * 1024, Wsel + (size_t)bn * 1024, As, Bs, acc, tid);

  const int lane = tid & 63, w = tid >> 6;
  const int wm = (w >> 1) * 64, wn = (w & 1) * 64;
  const int lr = lane & 15, lg = lane >> 4;
  const bool rope = (z < 2);
  const bool odd = lane & 1;
#pragma unroll
  for (int mi = 0; mi < 4; ++mi) {
#pragma unroll
    for (int ni = 0; ni < 4; ++ni) {
#pragma unroll
      for (int reg = 0; reg < 4; ++reg) {
        const int r = bm + wm + mi * 16 + lg * 4 + reg;  // D row -> (b,s)
        const int e = bn + wn + ni * 16 + lr;            // D col -> (h,d)
        float val = acc[mi][ni][reg];
        const float partner = __shfl_xor(val, 1);
        const int s = r & 2047, b = r >> 11;
        const int h = e >> 6, d = e & 63;
        float outv = val;
        if (rope) {
          const int i = d >> 1;
          const float c = ctab[s * 32 + i];
          const float sn = stab[s * 32 + i];
          outv = odd ? (val * c + partner * sn) : (val * c - partner * sn);
        }
        if (z == 2)
          Out[((size_t)(b * 16 + h) * 64 + d) * 2048 + s] = f2bf(outv);
        else
          Out[((size_t)(b * 16 + h) * 2048 + s) * 64 + d] = f2bf(outv);
      }
    }
  }
}

// ---------- stage 2: causal flash attention ----------
// grid (16 q-tiles of 128 [reversed], 32 bh). 4 waves, each owns 32 q rows.
// KV tile 64, double-buffered staging with counted vmcnt.
__global__ __launch_bounds__(256) void k_attn(
    const unsigned short* __restrict__ Q, const unsigned short* __restrict__ K,
    const unsigned short* __restrict__ Vt, unsigned short* __restrict__ O) {
  __shared__ __align__(16) unsigned short Ks[2][64 * 64];  // swizzled [kv][d]
  __shared__ __align__(16) unsigned short Vs[2][64 * 64];  // swizzled [dv][kv]
  __shared__ __align__(16) unsigned short Pl[4][32 * 68];
  const int bh = blockIdx.y;
  const int qt = gridDim.x - 1 - blockIdx.x;  // heavy blocks first
  const int qb = qt * 128;
  const int tid = threadIdx.x, lane = tid & 63, w = tid >> 6;
  const int lr = lane & 15, lg = lane >> 4;
  const unsigned short* Qg = Q + (size_t)bh * 2048 * 64;
  const unsigned short* Kg = K + (size_t)bh * 2048 * 64;
  const unsigned short* Vg = Vt + (size_t)bh * 64 * 2048;
  const int qrow = qb + w * 32;

  // Q fragments: 32 rows x 64 d per wave
  bf16x8 qf[2][2];
#pragma unroll
  for (int mi = 0; mi < 2; ++mi)
#pragma unroll
    for (int h = 0; h < 2; ++h)
      qf[mi][h] = *(const bf16x8*)(Qg + (qrow + mi * 16 + lr) * 64 + h * 32 + lg * 8);

  // ones B-fragment (for row-sum via MFMA)
  u16x8 ouv;
#pragma unroll
  for (int j = 0; j < 8; ++j) ouv[j] = 0x3F80;  // bf16 1.0
  const bf16x8 onesf = __builtin_bit_cast(bf16x8, ouv);

  f32x4 oacc[2][4] = {};
  float mrow[2][4], lrow[2][4];
#pragma unroll
  for (int mi = 0; mi < 2; ++mi)
#pragma unroll
    for (int r = 0; r < 4; ++r) { mrow[mi][r] = -__builtin_inff(); lrow[mi][r] = 0.f; }

  // staging: chunk c -> row r=c>>3, slot j=c&7; source col-chunk = j ^ (r&7)
  const int r0 = tid >> 3, j0 = tid & 7, cs0 = j0 ^ (r0 & 7);
  const int r1 = r0 + 32, cs1 = j0 ^ (r1 & 7);

  auto stage = [&](int buf, int kv0) {
    load_lds16(Kg + (size_t)(kv0 + r0) * 64 + cs0 * 8, &Ks[buf][0] + tid * 8);
    load_lds16(Kg + (size_t)(kv0 + r1) * 64 + cs1 * 8, &Ks[buf][0] + (tid + 256) * 8);
    load_lds16(Vg + (size_t)r0 * 2048 + kv0 + cs0 * 8, &Vs[buf][0] + tid * 8);
    load_lds16(Vg + (size_t)r1 * 2048 + kv0 + cs1 * 8, &Vs[buf][0] + (tid + 256) * 8);
  };

  const float SCL = 0.125f * 1.44269504088896f;  // 1/sqrt(64) * log2(e)
  const int T = qt * 2 + 2;
  stage(0, 0);
  for (int t = 0; t < T; ++t) {
    const int kv0 = t * 64;
    const int cur = t & 1;
    if (t + 1 < T) {
      stage(cur ^ 1, kv0 + 64);
      asm volatile("s_waitcnt vmcnt(4)" ::: "memory");
    } else {
      asm volatile("s_waitcnt vmcnt(0)" ::: "memory");
    }
    __builtin_amdgcn_s_barrier();

    if (kv0 < qrow + 32) {  // wave-uniform: tile has unmasked work
      const unsigned short* Kb = &Ks[cur][0];
      const unsigned short* Vb = &Vs[cur][0];

      // ---- S = Q K^T : 32 q x 64 kv ----
      f32x4 sacc[2][4];
#pragma unroll
      for (int nt = 0; nt < 4; ++nt) {
        const int row = nt * 16 + lr;
        const bf16x8 kb0 = *(const bf16x8*)(Kb + row * 64 + ((lg ^ (row & 7)) * 8));
        const bf16x8 kb1 = *(const bf16x8*)(Kb + row * 64 + (((lg + 4) ^ (row & 7)) * 8));
#pragma unroll
        for (int mi = 0; mi < 2; ++mi) {
          f32x4 z = {0.f, 0.f, 0.f, 0.f};
          z = __builtin_amdgcn_mfma_f32_16x16x32_bf16(qf[mi][0], kb0, z, 0, 0, 0);
          sacc[mi][nt] = __builtin_amdgcn_mfma_f32_16x16x32_bf16(qf[mi][1], kb1, z, 0, 0, 0);
        }
      }

      // ---- scale (+mask) + row max (local + 4-step butterfly over lr) ----
      const bool needmask = (kv0 + 63 > qrow);  // wave-uniform
      float pm[2][4];
#pragma unroll
      for (int mi = 0; mi < 2; ++mi)
#pragma unroll
        for (int r = 0; r < 4; ++r) pm[mi][r] = -__builtin_inff();
#pragma unroll
      for (int mi = 0; mi < 2; ++mi)
#pragma unroll
        for (int nt = 0; nt < 4; ++nt)
#pragma unroll
          for (int reg = 0; reg < 4; ++reg) {
            float sv = sacc[mi][nt][reg] * SCL;
            if (needmask) {
              const int kg = kv0 + nt * 16 + lr;
              const int qg = qrow + mi * 16 + lg * 4 + reg;
              if (kg > qg) sv = -__builtin_inff();
            }
            sacc[mi][nt][reg] = sv;
            pm[mi][reg] = fmaxf(pm[mi][reg], sv);
          }
#pragma unroll
      for (int off = 1; off < 16; off <<= 1)
#pragma unroll
        for (int mi = 0; mi < 2; ++mi)
#pragma unroll
          for (int reg = 0; reg < 4; ++reg)
            pm[mi][reg] = fmaxf(pm[mi][reg], __shfl_xor(pm[mi][reg], off));

      // ---- online softmax (exp2 domain) ----
      float al[2][4];
#pragma unroll
      for (int mi = 0; mi < 2; ++mi)
#pragma unroll
        for (int reg = 0; reg < 4; ++reg) {
          const float mn = fmaxf(mrow[mi][reg], pm[mi][reg]);
          al[mi][reg] = exp2f(mrow[mi][reg] - mn);
          mrow[mi][reg] = mn;
#pragma unroll
          for (int nt = 0; nt < 4; ++nt)
            sacc[mi][nt][reg] = exp2f(sacc[mi][nt][reg] - mn);
#pragma unroll
          for (int nt = 0; nt < 4; ++nt) oacc[mi][nt][reg] *= al[mi][reg];
        }

      // ---- P relayout through padded wave-local LDS (no barrier) ----
      unsigned short* Pw = Pl[w];
#pragma unroll
      for (int mi = 0; mi < 2; ++mi)
#pragma unroll
        for (int nt = 0; nt < 4; ++nt)
#pragma unroll
          for (int reg = 0; reg < 4; ++reg)
            Pw[(mi * 16 + lg * 4 + reg) * 68 + nt * 16 + lr] =
                f2bf(sacc[mi][nt][reg]);
      bf16x8 pa[2][2];
#pragma unroll
      for (int mi = 0; mi < 2; ++mi)
#pragma unroll
        for (int ks = 0; ks < 2; ++ks)
          pa[mi][ks] = *(const bf16x8*)(Pw + (mi * 16 + lr) * 68 + ks * 32 + lg * 8);

      // ---- row-sum via ones-MFMA: every lane gets sum over kv ----
#pragma unroll
      for (int mi = 0; mi < 2; ++mi) {
        f32x4 z = {0.f, 0.f, 0.f, 0.f};
        z = __builtin_amdgcn_mfma_f32_16x16x32_bf16(pa[mi][0], onesf, z, 0, 0, 0);
        z = __builtin_amdgcn_mfma_f32_16x16x32_bf16(pa[mi][1], onesf, z, 0, 0, 0);
#pragma unroll
        for (int reg = 0; reg < 4; ++reg)
          lrow[mi][reg] = lrow[mi][reg] * al[mi][reg] + z[reg];
      }

      // ---- O += P V : 32 q x 64 dv ----
#pragma unroll
      for (int nt = 0; nt < 4; ++nt) {
        const int row = nt * 16 + lr;
        const bf16x8 vb0 = *(const bf16x8*)(Vb + row * 64 + ((lg ^ (row & 7)) * 8));
        const bf16x8 vb1 = *(const bf16x8*)(Vb + row * 64 + (((lg + 4) ^ (row & 7)) * 8));
#pragma unroll
        for (int mi = 0; mi < 2; ++mi) {
          oacc[mi][nt] = __builtin_amdgcn_mfma_f32_16x16x32_bf16(pa[mi][0], vb0,
                                                                 oacc[mi][nt], 0, 0, 0);
          oacc[mi][nt] = __builtin_amdgcn_mfma_f32_16x16x32_bf16(pa[mi][1], vb1,
                                                                 oacc[mi][nt], 0, 0, 0);
        }
      }
    }
    __builtin_amdgcn_s_barrier();
  }

  // ---- normalize + write attn out as bf16 [B][S][H*64] ----
  const int b = bh >> 4, h = bh & 15;
#pragma unroll
  for (int mi = 0; mi < 2; ++mi)
#pragma unroll
    for (int reg = 0; reg < 4; ++reg) {
      const float inv = 1.0f / lrow[mi][reg];
      const int s = qrow + mi * 16 + lg * 4 + reg;
#pragma unroll
      for (int nt = 0; nt < 4; ++nt) {
        const int dv = nt * 16 + lr;
        O[((size_t)b * 2048 + s) * 1024 + h * 64 + dv] = f2bf(oacc[mi][nt][reg] * inv);
      }
    }
}

// ---------- stage 3: output projection, f32 epilogue ----------
__global__ __launch_bounds__(256) void k_out(const unsigned short* __restrict__ Ab,
                                             const unsigned short* __restrict__ Wo,
                                             float* __restrict__ Out) {
  __shared__ __align__(16) unsigned short As[2 * 128 * 32];
  __shared__ __align__(16) unsigned short Bs[2 * 128 * 32];
  const int tid = threadIdx.x;
  const int bm = blockIdx.x * 128, bn = blockIdx.y * 128;
  f32x4 acc[4][4] = {};
  gemm_core_1024(Ab + (size_t)bm * 1024, Wo + (size_t)bn * 1024, As, Bs, acc, tid);
  const int lane = tid & 63, w = tid >> 6;
  const int wm = (w >> 1) * 64, wn = (w & 1) * 64;
  const int lr = lane & 15, lg = lane >> 4;
#pragma unroll
  for (int mi = 0; mi < 4; ++mi)
#pragma unroll
    for (int ni = 0; ni < 4; ++ni)
#pragma unroll
      for (int reg = 0; reg < 4; ++reg) {
        const int r = bm + wm + mi * 16 + lg * 4 + reg;
        const int e = bn + wn + ni * 16 + lr;
        Out[(size_t)r * 1024 + e] = acc[mi][ni][reg];
      }
}

// ---------- launch ----------
extern "C" void kernel_launch(void* const* d_in, const int* in_sizes, int n_in,
                              void* d_out, int out_size, void* d_ws, size_t ws_size,
                              hipStream_t stream) {
  const float* x = (const float*)d_in[0];
  const float* Wq = (const float*)d_in[1];
  const float* Wk = (const float*)d_in[2];
  const float* Wv = (const float*)d_in[3];
  const float* Wo = (const float*)d_in[4];
  const int* tpos = (const int*)d_in[5];
  float* out = (float*)d_out;
  char* ws = (char*)d_ws;
  const size_t MB = 1024 * 1024;
  unsigned short* xb = (unsigned short*)(ws);             // 8 MB
  unsigned short* wqb = (unsigned short*)(ws + 8 * MB);   // 2 MB
  unsigned short* wkb = (unsigned short*)(ws + 10 * MB);
  unsigned short* wvb = (unsigned short*)(ws + 12 * MB);
  unsigned short* wob = (unsigned short*)(ws + 14 * MB);
  unsigned short* Qb = (unsigned short*)(ws + 16 * MB);   // 8 MB each
  unsigned short* Kb = (unsigned short*)(ws + 24 * MB);
  unsigned short* Vtb = (unsigned short*)(ws + 32 * MB);  // transposed V
  unsigned short* Ab = (unsigned short*)(ws + 40 * MB);
  float* ctab = (float*)(ws + 48 * MB);                   // 256 KB
  float* stab = (float*)(ws + 48 * MB + 256 * 1024);

  k_convert<<<dim3(8192), dim3(256), 0, stream>>>(x, Wq, Wk, Wv, Wo, xb, wqb, wkb,
                                                  wvb, wob);
  k_rope_tab<<<dim3(256), dim3(256), 0, stream>>>(tpos, ctab, stab);
  k_proj<<<dim3(32, 8, 3), dim3(256), 0, stream>>>(xb, wqb, wkb, wvb, ctab, stab,
                                                   Qb, Kb, Vtb);
  k_attn<<<dim3(16, 32), dim3(256), 0, stream>>>(Qb, Kb, Vtb, Ab);
  k_out<<<dim3(32, 8), dim3(256), 0, stream>>>(Ab, wob, out);
}

// Round 4
// 196.495 us; speedup vs baseline: 1.7617x; 1.1509x over previous
//
#include <hip/hip_runtime.h>

typedef __bf16 bf16x8 __attribute__((ext_vector_type(8)));
typedef float f32x4 __attribute__((ext_vector_type(4)));
typedef unsigned short u16x8 __attribute__((ext_vector_type(8)));

// ---------- helpers ----------

__device__ __forceinline__ unsigned short f2bf(float f) {
  unsigned u = __builtin_bit_cast(unsigned, f);
  u = (u + 0x7FFFu + ((u >> 16) & 1u)) >> 16;   // RNE
  return (unsigned short)u;
}

__device__ __forceinline__ void load_lds16(const void* g, void* l) {
  __builtin_amdgcn_global_load_lds(
      (__attribute__((address_space(1))) void*)g,
      (__attribute__((address_space(3))) void*)l, 16, 0, 0);
}

// ---------- stage 0: dtype convert ----------
__global__ __launch_bounds__(256) void k_convert(
    const float* __restrict__ x,
    const float* __restrict__ wq, const float* __restrict__ wk,
    const float* __restrict__ wv, const float* __restrict__ wo,
    unsigned short* __restrict__ xb,
    unsigned short* __restrict__ wqb, unsigned short* __restrict__ wkb,
    unsigned short* __restrict__ wvb, unsigned short* __restrict__ wob) {
  const int g = blockIdx.x * 256 + threadIdx.x;  // exactly 2M threads
  const float* src;
  unsigned short* dst;
  int off;
  if (g < (1 << 20)) {
    src = x; dst = xb; off = g;
  } else {
    const int q = g - (1 << 20);
    const int t = q >> 18;
    off = q & ((1 << 18) - 1);
    src = (t == 0) ? wq : (t == 1) ? wk : (t == 2) ? wv : wo;
    dst = (t == 0) ? wqb : (t == 1) ? wkb : (t == 2) ? wvb : wob;
  }
  const float4 v = ((const float4*)src)[off];
  ushort4 r;
  r.x = f2bf(v.x); r.y = f2bf(v.y); r.z = f2bf(v.z); r.w = f2bf(v.w);
  ((ushort4*)dst)[off] = r;
}

// ---------- stage 0b: rope table ----------
__global__ __launch_bounds__(256) void k_rope_tab(const int* __restrict__ tpos,
                                                  float* __restrict__ ct,
                                                  float* __restrict__ st) {
  const int idx = blockIdx.x * 256 + threadIdx.x;  // 2048*32 = 64K
  const int s = idx >> 5, i = idx & 31;
  const double p = (double)tpos[s];
  const double f = p * pow(10000.0, -(double)(2 * i) / 64.0);
  ct[idx] = (float)cos(f);
  st[idx] = (float)sin(f);
}

// ---------- GEMM core: C[128x128] += A[128xK] * B[128xK]^T, K=1024, BK=32 ----------
// 3-deep staging pipeline with counted vmcnt. As/Bs are 3*128*32 elems.
__device__ __forceinline__ void gemm_core_1024(
    const unsigned short* __restrict__ Ag,  // at row bm
    const unsigned short* __restrict__ Bg,  // at row bn
    unsigned short* As, unsigned short* Bs, f32x4 (&acc)[4][4], int tid) {
  const int lane = tid & 63;
  const int w = tid >> 6;
  const int wm = (w >> 1) * 64;
  const int wn = (w & 1) * 64;
  const int lr = lane & 15;
  const int lg8 = (lane >> 4) * 8;
  const int c0 = tid, c1 = 256 + tid;
  const int ar0 = c0 >> 2, ac0 = (c0 & 3) * 8;
  const int ar1 = c1 >> 2, ac1 = (c1 & 3) * 8;

  auto stage = [&](int buf, int kt) {
    unsigned short* Ab = As + buf * 4096;
    unsigned short* Bb = Bs + buf * 4096;
    load_lds16(Ag + ar0 * 1024 + kt + ac0, Ab + c0 * 8);
    load_lds16(Ag + ar1 * 1024 + kt + ac1, Ab + c1 * 8);
    load_lds16(Bg + ar0 * 1024 + kt + ac0, Bb + c0 * 8);
    load_lds16(Bg + ar1 * 1024 + kt + ac1, Bb + c1 * 8);
  };

  stage(0, 0);
  stage(1, 32);
  int cur = 0;
  for (int ki = 0; ki < 32; ++ki) {
    if (ki + 2 < 32) {
      int nb = cur + 2; if (nb >= 3) nb -= 3;
      stage(nb, (ki + 2) * 32);
      asm volatile("s_waitcnt vmcnt(8)" ::: "memory");
    } else if (ki + 1 < 32) {
      asm volatile("s_waitcnt vmcnt(4)" ::: "memory");
    } else {
      asm volatile("s_waitcnt vmcnt(0)" ::: "memory");
    }
    __builtin_amdgcn_s_barrier();
    const unsigned short* Ab = As + cur * 4096;
    const unsigned short* Bb = Bs + cur * 4096;
    bf16x8 af[4], bfv[4];
#pragma unroll
    for (int mi = 0; mi < 4; ++mi)
      af[mi] = *(const bf16x8*)(Ab + (wm + mi * 16 + lr) * 32 + lg8);
#pragma unroll
    for (int ni = 0; ni < 4; ++ni)
      bfv[ni] = *(const bf16x8*)(Bb + (wn + ni * 16 + lr) * 32 + lg8);
    __builtin_amdgcn_s_setprio(1);
#pragma unroll
    for (int mi = 0; mi < 4; ++mi)
#pragma unroll
      for (int ni = 0; ni < 4; ++ni)
        acc[mi][ni] = __builtin_amdgcn_mfma_f32_16x16x32_bf16(
            af[mi], bfv[ni], acc[mi][ni], 0, 0, 0);
    __builtin_amdgcn_s_setprio(0);
    __builtin_amdgcn_s_barrier();
    ++cur; if (cur == 3) cur = 0;
  }
}

// ---------- stage 1: q/k/v projection + rope ----------
// Q,K out: bf16 [B*H][S][64]. V out: TRANSPOSED bf16 [B*H][64][S] (for attn staging).
__global__ __launch_bounds__(256) void k_proj(
    const unsigned short* __restrict__ Xb,
    const unsigned short* __restrict__ Wq, const unsigned short* __restrict__ Wk,
    const unsigned short* __restrict__ Wv,
    const float* __restrict__ ctab, const float* __restrict__ stab,
    unsigned short* __restrict__ Qo, unsigned short* __restrict__ Ko,
    unsigned short* __restrict__ Vo) {
  __shared__ __align__(16) unsigned short As[3 * 128 * 32];
  __shared__ __align__(16) unsigned short Bs[3 * 128 * 32];
  const int z = blockIdx.z;
  const unsigned short* Wsel = (z == 0) ? Wq : (z == 1) ? Wk : Wv;
  unsigned short* Out = (z == 0) ? Qo : (z == 1) ? Ko : Vo;
  const int tid = threadIdx.x;
  const int bm = blockIdx.x * 128, bn = blockIdx.y * 128;
  f32x4 acc[4][4] = {};
  gemm_core_1024(Xb + (size_t)bm * 1024, Wsel + (size_t)bn * 1024, As, Bs, acc, tid);

  const int lane = tid & 63, w = tid >> 6;
  const int wm = (w >> 1) * 64, wn = (w & 1) * 64;
  const int lr = lane & 15, lg = lane >> 4;
  const bool rope = (z < 2);
  const bool odd = lane & 1;
#pragma unroll
  for (int mi = 0; mi < 4; ++mi) {
#pragma unroll
    for (int ni = 0; ni < 4; ++ni) {
#pragma unroll
      for (int reg = 0; reg < 4; ++reg) {
        const int r = bm + wm + mi * 16 + lg * 4 + reg;  // D row -> (b,s)
        const int e = bn + wn + ni * 16 + lr;            // D col -> (h,d)
        float val = acc[mi][ni][reg];
        const float partner = __shfl_xor(val, 1);
        const int s = r & 2047, b = r >> 11;
        const int h = e >> 6, d = e & 63;
        float outv = val;
        if (rope) {
          const int i = d >> 1;
          const float c = ctab[s * 32 + i];
          const float sn = stab[s * 32 + i];
          outv = odd ? (val * c + partner * sn) : (val * c - partner * sn);
        }
        if (z == 2)
          Out[((size_t)(b * 16 + h) * 64 + d) * 2048 + s] = f2bf(outv);
        else
          Out[((size_t)(b * 16 + h) * 2048 + s) * 64 + d] = f2bf(outv);
      }
    }
  }
}

// ---------- stage 2: causal flash attention ----------
// grid (16, 32). Balanced qt pairing: qt = x for y<16, 15-x for y>=16, so the
// two co-resident blocks per CU (b and b+256 under round-robin) sum to 36 tiles.
// 4 waves, each owns 32 q rows. KV tile 64, 3-deep staging, counted vmcnt.
__global__ __launch_bounds__(256) void k_attn(
    const unsigned short* __restrict__ Q, const unsigned short* __restrict__ K,
    const unsigned short* __restrict__ Vt, unsigned short* __restrict__ O) {
  __shared__ __align__(16) unsigned short Ks[3][64 * 64];  // swizzled [kv][d]
  __shared__ __align__(16) unsigned short Vs[3][64 * 64];  // swizzled [dv][kv]
  __shared__ __align__(16) unsigned short Pl[4][32 * 68];
  const int bh = blockIdx.y;
  const int qt = (blockIdx.y < 16) ? blockIdx.x : 15 - blockIdx.x;
  const int qb = qt * 128;
  const int tid = threadIdx.x, lane = tid & 63, w = tid >> 6;
  const int lr = lane & 15, lg = lane >> 4;
  const unsigned short* Qg = Q + (size_t)bh * 2048 * 64;
  const unsigned short* Kg = K + (size_t)bh * 2048 * 64;
  const unsigned short* Vg = Vt + (size_t)bh * 64 * 2048;
  const int qrow = qb + w * 32;

  // Q fragments: 32 rows x 64 d per wave
  bf16x8 qf[2][2];
#pragma unroll
  for (int mi = 0; mi < 2; ++mi)
#pragma unroll
    for (int h = 0; h < 2; ++h)
      qf[mi][h] = *(const bf16x8*)(Qg + (qrow + mi * 16 + lr) * 64 + h * 32 + lg * 8);

  // ones B-fragment (for row-sum via MFMA)
  u16x8 ouv;
#pragma unroll
  for (int j = 0; j < 8; ++j) ouv[j] = 0x3F80;  // bf16 1.0
  const bf16x8 onesf = __builtin_bit_cast(bf16x8, ouv);

  f32x4 oacc[2][4] = {};
  float mrow[2][4], lrow[2][4];
#pragma unroll
  for (int mi = 0; mi < 2; ++mi)
#pragma unroll
    for (int r = 0; r < 4; ++r) { mrow[mi][r] = -__builtin_inff(); lrow[mi][r] = 0.f; }

  // staging: chunk c -> row r=c>>3, slot j=c&7; source col-chunk = j ^ (r&7)
  const int r0 = tid >> 3, j0 = tid & 7, cs0 = j0 ^ (r0 & 7);
  const int r1 = r0 + 32, cs1 = j0 ^ (r1 & 7);

  auto stage = [&](int buf, int kv0) {
    load_lds16(Kg + (size_t)(kv0 + r0) * 64 + cs0 * 8, &Ks[buf][0] + tid * 8);
    load_lds16(Kg + (size_t)(kv0 + r1) * 64 + cs1 * 8, &Ks[buf][0] + (tid + 256) * 8);
    load_lds16(Vg + (size_t)r0 * 2048 + kv0 + cs0 * 8, &Vs[buf][0] + tid * 8);
    load_lds16(Vg + (size_t)r1 * 2048 + kv0 + cs1 * 8, &Vs[buf][0] + (tid + 256) * 8);
  };

  const float SCL = 0.125f * 1.44269504088896f;  // 1/sqrt(64) * log2(e)
  const int T = qt * 2 + 2;
  stage(0, 0);
  stage(1, 64);
  int cur = 0;
  for (int t = 0; t < T; ++t) {
    const int kv0 = t * 64;
    if (t + 2 < T) {
      int nb = cur + 2; if (nb >= 3) nb -= 3;
      stage(nb, kv0 + 128);
      asm volatile("s_waitcnt vmcnt(8)" ::: "memory");
    } else if (t + 1 < T) {
      asm volatile("s_waitcnt vmcnt(4)" ::: "memory");
    } else {
      asm volatile("s_waitcnt vmcnt(0)" ::: "memory");
    }
    __builtin_amdgcn_s_barrier();

    if (kv0 < qrow + 32) {  // wave-uniform: tile has unmasked work
      const unsigned short* Kb = &Ks[cur][0];
      const unsigned short* Vb = &Vs[cur][0];

      // ---- S = Q K^T : 32 q x 64 kv (raw scores) ----
      f32x4 sacc[2][4];
      __builtin_amdgcn_s_setprio(1);
#pragma unroll
      for (int nt = 0; nt < 4; ++nt) {
        const int row = nt * 16 + lr;
        const bf16x8 kb0 = *(const bf16x8*)(Kb + row * 64 + ((lg ^ (row & 7)) * 8));
        const bf16x8 kb1 = *(const bf16x8*)(Kb + row * 64 + (((lg + 4) ^ (row & 7)) * 8));
#pragma unroll
        for (int mi = 0; mi < 2; ++mi) {
          f32x4 z = {0.f, 0.f, 0.f, 0.f};
          z = __builtin_amdgcn_mfma_f32_16x16x32_bf16(qf[mi][0], kb0, z, 0, 0, 0);
          sacc[mi][nt] = __builtin_amdgcn_mfma_f32_16x16x32_bf16(qf[mi][1], kb1, z, 0, 0, 0);
        }
      }
      __builtin_amdgcn_s_setprio(0);

      // ---- causal mask (raw domain) + row max ----
      const bool needmask = (kv0 + 63 > qrow);  // wave-uniform
      float pm[2][4];
#pragma unroll
      for (int mi = 0; mi < 2; ++mi)
#pragma unroll
        for (int r = 0; r < 4; ++r) pm[mi][r] = -__builtin_inff();
#pragma unroll
      for (int mi = 0; mi < 2; ++mi)
#pragma unroll
        for (int nt = 0; nt < 4; ++nt)
#pragma unroll
          for (int reg = 0; reg < 4; ++reg) {
            float sv = sacc[mi][nt][reg];
            if (needmask) {
              const int kg = kv0 + nt * 16 + lr;
              const int qg = qrow + mi * 16 + lg * 4 + reg;
              if (kg > qg) sv = -__builtin_inff();
            }
            sacc[mi][nt][reg] = sv;
            pm[mi][reg] = fmaxf(pm[mi][reg], sv);
          }
#pragma unroll
      for (int off = 1; off < 16; off <<= 1)
#pragma unroll
        for (int mi = 0; mi < 2; ++mi)
#pragma unroll
          for (int reg = 0; reg < 4; ++reg)
            pm[mi][reg] = fmaxf(pm[mi][reg], __shfl_xor(pm[mi][reg], off));

      // ---- online softmax (exp2 domain, deferred rescale when max didn't grow) ----
      float gm = -1.f;
#pragma unroll
      for (int mi = 0; mi < 2; ++mi)
#pragma unroll
        for (int reg = 0; reg < 4; ++reg)
          gm = fmaxf(gm, pm[mi][reg] - mrow[mi][reg]);
      float al[2][4], msc[2][4];
      if (__any(gm > 0.f)) {
#pragma unroll
        for (int mi = 0; mi < 2; ++mi)
#pragma unroll
          for (int reg = 0; reg < 4; ++reg) {
            const float mn = fmaxf(mrow[mi][reg], pm[mi][reg]);
            al[mi][reg] = exp2f(SCL * (mrow[mi][reg] - mn));
            mrow[mi][reg] = mn;
            msc[mi][reg] = SCL * mn;
#pragma unroll
            for (int nt = 0; nt < 4; ++nt) oacc[mi][nt][reg] *= al[mi][reg];
            lrow[mi][reg] *= al[mi][reg];
          }
      } else {
#pragma unroll
        for (int mi = 0; mi < 2; ++mi)
#pragma unroll
          for (int reg = 0; reg < 4; ++reg) msc[mi][reg] = SCL * mrow[mi][reg];
      }
#pragma unroll
      for (int mi = 0; mi < 2; ++mi)
#pragma unroll
        for (int nt = 0; nt < 4; ++nt)
#pragma unroll
          for (int reg = 0; reg < 4; ++reg)
            sacc[mi][nt][reg] = exp2f(sacc[mi][nt][reg] * SCL - msc[mi][reg]);

      // ---- P relayout through padded wave-local LDS (no barrier) ----
      unsigned short* Pw = Pl[w];
#pragma unroll
      for (int mi = 0; mi < 2; ++mi)
#pragma unroll
        for (int nt = 0; nt < 4; ++nt)
#pragma unroll
          for (int reg = 0; reg < 4; ++reg)
            Pw[(mi * 16 + lg * 4 + reg) * 68 + nt * 16 + lr] =
                f2bf(sacc[mi][nt][reg]);
      bf16x8 pa[2][2];
#pragma unroll
      for (int mi = 0; mi < 2; ++mi)
#pragma unroll
        for (int ks = 0; ks < 2; ++ks)
          pa[mi][ks] = *(const bf16x8*)(Pw + (mi * 16 + lr) * 68 + ks * 32 + lg * 8);

      // ---- row-sum via ones-MFMA + O += P V ----
      __builtin_amdgcn_s_setprio(1);
#pragma unroll
      for (int mi = 0; mi < 2; ++mi) {
        f32x4 z = {0.f, 0.f, 0.f, 0.f};
        z = __builtin_amdgcn_mfma_f32_16x16x32_bf16(pa[mi][0], onesf, z, 0, 0, 0);
        z = __builtin_amdgcn_mfma_f32_16x16x32_bf16(pa[mi][1], onesf, z, 0, 0, 0);
#pragma unroll
        for (int reg = 0; reg < 4; ++reg)
          lrow[mi][reg] += z[reg];
      }
#pragma unroll
      for (int nt = 0; nt < 4; ++nt) {
        const int row = nt * 16 + lr;
        const bf16x8 vb0 = *(const bf16x8*)(Vb + row * 64 + ((lg ^ (row & 7)) * 8));
        const bf16x8 vb1 = *(const bf16x8*)(Vb + row * 64 + (((lg + 4) ^ (row & 7)) * 8));
#pragma unroll
        for (int mi = 0; mi < 2; ++mi) {
          oacc[mi][nt] = __builtin_amdgcn_mfma_f32_16x16x32_bf16(pa[mi][0], vb0,
                                                                 oacc[mi][nt], 0, 0, 0);
          oacc[mi][nt] = __builtin_amdgcn_mfma_f32_16x16x32_bf16(pa[mi][1], vb1,
                                                                 oacc[mi][nt], 0, 0, 0);
        }
      }
      __builtin_amdgcn_s_setprio(0);
    }
    __builtin_amdgcn_s_barrier();
    ++cur; if (cur == 3) cur = 0;
  }

  // ---- normalize + write attn out as bf16 [B][S][H*64] ----
  const int b = bh >> 4, h = bh & 15;
#pragma unroll
  for (int mi = 0; mi < 2; ++mi)
#pragma unroll
    for (int reg = 0; reg < 4; ++reg) {
      const float inv = 1.0f / lrow[mi][reg];
      const int s = qrow + mi * 16 + lg * 4 + reg;
#pragma unroll
      for (int nt = 0; nt < 4; ++nt) {
        const int dv = nt * 16 + lr;
        O[((size_t)b * 2048 + s) * 1024 + h * 64 + dv] = f2bf(oacc[mi][nt][reg] * inv);
      }
    }
}

// ---------- stage 3: output projection, f32 epilogue ----------
__global__ __launch_bounds__(256) void k_out(const unsigned short* __restrict__ Ab,
                                             const unsigned short* __restrict__ Wo,
                                             float* __restrict__ Out) {
  __shared__ __align__(16) unsigned short As[3 * 128 * 32];
  __shared__ __align__(16) unsigned short Bs[3 * 128 * 32];
  const int tid = threadIdx.x;
  const int bm = blockIdx.x * 128, bn = blockIdx.y * 128;
  f32x4 acc[4][4] = {};
  gemm_core_1024(Ab + (size_t)bm * 1024, Wo + (size_t)bn * 1024, As, Bs, acc, tid);
  const int lane = tid & 63, w = tid >> 6;
  const int wm = (w >> 1) * 64, wn = (w & 1) * 64;
  const int lr = lane & 15, lg = lane >> 4;
#pragma unroll
  for (int mi = 0; mi < 4; ++mi)
#pragma unroll
    for (int ni = 0; ni < 4; ++ni)
#pragma unroll
      for (int reg = 0; reg < 4; ++reg) {
        const int r = bm + wm + mi * 16 + lg * 4 + reg;
        const int e = bn + wn + ni * 16 + lr;
        Out[(size_t)r * 1024 + e] = acc[mi][ni][reg];
      }
}

// ---------- launch ----------
extern "C" void kernel_launch(void* const* d_in, const int* in_sizes, int n_in,
                              void* d_out, int out_size, void* d_ws, size_t ws_size,
                              hipStream_t stream) {
  const float* x = (const float*)d_in[0];
  const float* Wq = (const float*)d_in[1];
  const float* Wk = (const float*)d_in[2];
  const float* Wv = (const float*)d_in[3];
  const float* Wo = (const float*)d_in[4];
  const int* tpos = (const int*)d_in[5];
  float* out = (float*)d_out;
  char* ws = (char*)d_ws;
  const size_t MB = 1024 * 1024;
  unsigned short* xb = (unsigned short*)(ws);             // 8 MB
  unsigned short* wqb = (unsigned short*)(ws + 8 * MB);   // 2 MB
  unsigned short* wkb = (unsigned short*)(ws + 10 * MB);
  unsigned short* wvb = (unsigned short*)(ws + 12 * MB);
  unsigned short* wob = (unsigned short*)(ws + 14 * MB);
  unsigned short* Qb = (unsigned short*)(ws + 16 * MB);   // 8 MB each
  unsigned short* Kb = (unsigned short*)(ws + 24 * MB);
  unsigned short* Vtb = (unsigned short*)(ws + 32 * MB);  // transposed V
  unsigned short* Ab = (unsigned short*)(ws + 40 * MB);
  float* ctab = (float*)(ws + 48 * MB);                   // 256 KB
  float* stab = (float*)(ws + 48 * MB + 256 * 1024);

  k_convert<<<dim3(8192), dim3(256), 0, stream>>>(x, Wq, Wk, Wv, Wo, xb, wqb, wkb,
                                                  wvb, wob);
  k_rope_tab<<<dim3(256), dim3(256), 0, stream>>>(tpos, ctab, stab);
  k_proj<<<dim3(32, 8, 3), dim3(256), 0, stream>>>(xb, wqb, wkb, wvb, ctab, stab,
                                                   Qb, Kb, Vtb);
  k_attn<<<dim3(16, 32), dim3(256), 0, stream>>>(Qb, Kb, Vtb, Ab);
  k_out<<<dim3(32, 8), dim3(256), 0, stream>>>(Ab, wob, out);
}

// Round 5
// 185.042 us; speedup vs baseline: 1.8707x; 1.0619x over previous
//
#include <hip/hip_runtime.h>

typedef __bf16 bf16x8 __attribute__((ext_vector_type(8)));
typedef float f32x4 __attribute__((ext_vector_type(4)));
typedef unsigned short u16x8 __attribute__((ext_vector_type(8)));

// ---------- helpers ----------

__device__ __forceinline__ unsigned short f2bf(float f) {
  unsigned u = __builtin_bit_cast(unsigned, f);
  u = (u + 0x7FFFu + ((u >> 16) & 1u)) >> 16;   // RNE
  return (unsigned short)u;
}

__device__ __forceinline__ void load_lds16(const void* g, void* l) {
  __builtin_amdgcn_global_load_lds(
      (__attribute__((address_space(1))) void*)g,
      (__attribute__((address_space(3))) void*)l, 16, 0, 0);
}

// ---------- stage 0: dtype convert ----------
__global__ __launch_bounds__(256) void k_convert(
    const float* __restrict__ x,
    const float* __restrict__ wq, const float* __restrict__ wk,
    const float* __restrict__ wv, const float* __restrict__ wo,
    unsigned short* __restrict__ xb,
    unsigned short* __restrict__ wqb, unsigned short* __restrict__ wkb,
    unsigned short* __restrict__ wvb, unsigned short* __restrict__ wob) {
  const int g = blockIdx.x * 256 + threadIdx.x;  // exactly 2M threads
  const float* src;
  unsigned short* dst;
  int off;
  if (g < (1 << 20)) {
    src = x; dst = xb; off = g;
  } else {
    const int q = g - (1 << 20);
    const int t = q >> 18;
    off = q & ((1 << 18) - 1);
    src = (t == 0) ? wq : (t == 1) ? wk : (t == 2) ? wv : wo;
    dst = (t == 0) ? wqb : (t == 1) ? wkb : (t == 2) ? wvb : wob;
  }
  const float4 v = ((const float4*)src)[off];
  ushort4 r;
  r.x = f2bf(v.x); r.y = f2bf(v.y); r.z = f2bf(v.z); r.w = f2bf(v.w);
  ((ushort4*)dst)[off] = r;
}

// ---------- stage 0b: rope table ----------
__global__ __launch_bounds__(256) void k_rope_tab(const int* __restrict__ tpos,
                                                  float* __restrict__ ct,
                                                  float* __restrict__ st) {
  const int idx = blockIdx.x * 256 + threadIdx.x;  // 2048*32 = 64K
  const int s = idx >> 5, i = idx & 31;
  const double p = (double)tpos[s];
  const double f = p * pow(10000.0, -(double)(2 * i) / 64.0);
  ct[idx] = (float)cos(f);
  st[idx] = (float)sin(f);
}

// ---------- GEMM core: C[128x128] += A[128xK] * B[128xK]^T, K=1024, BK=32 ----------
// 3-deep staging pipeline with counted vmcnt. As/Bs are 3*128*32 elems.
__device__ __forceinline__ void gemm_core_1024(
    const unsigned short* __restrict__ Ag,  // at row bm
    const unsigned short* __restrict__ Bg,  // at row bn
    unsigned short* As, unsigned short* Bs, f32x4 (&acc)[4][4], int tid) {
  const int lane = tid & 63;
  const int w = tid >> 6;
  const int wm = (w >> 1) * 64;
  const int wn = (w & 1) * 64;
  const int lr = lane & 15;
  const int lg8 = (lane >> 4) * 8;
  const int c0 = tid, c1 = 256 + tid;
  const int ar0 = c0 >> 2, ac0 = (c0 & 3) * 8;
  const int ar1 = c1 >> 2, ac1 = (c1 & 3) * 8;

  auto stage = [&](int buf, int kt) {
    unsigned short* Ab = As + buf * 4096;
    unsigned short* Bb = Bs + buf * 4096;
    load_lds16(Ag + ar0 * 1024 + kt + ac0, Ab + c0 * 8);
    load_lds16(Ag + ar1 * 1024 + kt + ac1, Ab + c1 * 8);
    load_lds16(Bg + ar0 * 1024 + kt + ac0, Bb + c0 * 8);
    load_lds16(Bg + ar1 * 1024 + kt + ac1, Bb + c1 * 8);
  };

  stage(0, 0);
  stage(1, 32);
  int cur = 0;
  for (int ki = 0; ki < 32; ++ki) {
    if (ki + 2 < 32) {
      int nb = cur + 2; if (nb >= 3) nb -= 3;
      stage(nb, (ki + 2) * 32);
      asm volatile("s_waitcnt vmcnt(8)" ::: "memory");
    } else if (ki + 1 < 32) {
      asm volatile("s_waitcnt vmcnt(4)" ::: "memory");
    } else {
      asm volatile("s_waitcnt vmcnt(0)" ::: "memory");
    }
    __builtin_amdgcn_s_barrier();
    const unsigned short* Ab = As + cur * 4096;
    const unsigned short* Bb = Bs + cur * 4096;
    bf16x8 af[4], bfv[4];
#pragma unroll
    for (int mi = 0; mi < 4; ++mi)
      af[mi] = *(const bf16x8*)(Ab + (wm + mi * 16 + lr) * 32 + lg8);
#pragma unroll
    for (int ni = 0; ni < 4; ++ni)
      bfv[ni] = *(const bf16x8*)(Bb + (wn + ni * 16 + lr) * 32 + lg8);
    __builtin_amdgcn_s_setprio(1);
#pragma unroll
    for (int mi = 0; mi < 4; ++mi)
#pragma unroll
      for (int ni = 0; ni < 4; ++ni)
        acc[mi][ni] = __builtin_amdgcn_mfma_f32_16x16x32_bf16(
            af[mi], bfv[ni], acc[mi][ni], 0, 0, 0);
    __builtin_amdgcn_s_setprio(0);
    __builtin_amdgcn_s_barrier();
    ++cur; if (cur == 3) cur = 0;
  }
}

// ---------- stage 1: q/k/v projection + rope ----------
// Q,K out: bf16 [B*H][S][64]. V out: TRANSPOSED bf16 [B*H][64][S] (for attn staging).
__global__ __launch_bounds__(256) void k_proj(
    const unsigned short* __restrict__ Xb,
    const unsigned short* __restrict__ Wq, const unsigned short* __restrict__ Wk,
    const unsigned short* __restrict__ Wv,
    const float* __restrict__ ctab, const float* __restrict__ stab,
    unsigned short* __restrict__ Qo, unsigned short* __restrict__ Ko,
    unsigned short* __restrict__ Vo) {
  __shared__ __align__(16) unsigned short As[3 * 128 * 32];
  __shared__ __align__(16) unsigned short Bs[3 * 128 * 32];
  const int z = blockIdx.z;
  const unsigned short* Wsel = (z == 0) ? Wq : (z == 1) ? Wk : Wv;
  unsigned short* Out = (z == 0) ? Qo : (z == 1) ? Ko : Vo;
  const int tid = threadIdx.x;
  const int bm = blockIdx.x * 128, bn = blockIdx.y * 128;
  f32x4 acc[4][4] = {};
  gemm_core_1024(Xb + (size_t)bm * 1024, Wsel + (size_t)bn * 1024, As, Bs, acc, tid);

  const int lane = tid & 63, w = tid >> 6;
  const int wm = (w >> 1) * 64, wn = (w & 1) * 64;
  const int lr = lane & 15, lg = lane >> 4;
  const bool rope = (z < 2);
  const bool odd = lane & 1;
#pragma unroll
  for (int mi = 0; mi < 4; ++mi) {
#pragma unroll
    for (int ni = 0; ni < 4; ++ni) {
#pragma unroll
      for (int reg = 0; reg < 4; ++reg) {
        const int r = bm + wm + mi * 16 + lg * 4 + reg;  // D row -> (b,s)
        const int e = bn + wn + ni * 16 + lr;            // D col -> (h,d)
        float val = acc[mi][ni][reg];
        const float partner = __shfl_xor(val, 1);
        const int s = r & 2047, b = r >> 11;
        const int h = e >> 6, d = e & 63;
        float outv = val;
        if (rope) {
          const int i = d >> 1;
          const float c = ctab[s * 32 + i];
          const float sn = stab[s * 32 + i];
          outv = odd ? (val * c + partner * sn) : (val * c - partner * sn);
        }
        if (z == 2)
          Out[((size_t)(b * 16 + h) * 64 + d) * 2048 + s] = f2bf(outv);
        else
          Out[((size_t)(b * 16 + h) * 2048 + s) * 64 + d] = f2bf(outv);
      }
    }
  }
}

// ---------- stage 2: causal flash attention, BARRIER-FREE ----------
// grid (16, 32) = 512 blocks. Swizzle: bh from L%32 (same-bh blocks land on one
// XCD under round-robin), qt paired (a, 23-a) so co-resident CU pairs sum to 34
// tiles. 4 independent waves/block, each owns 32 q rows; K double-buffered in
// registers, V staged into wave-private LDS (XOR-swizzled); no s_barrier at all.
__global__ __launch_bounds__(256, 2) void k_attn(
    const unsigned short* __restrict__ Q, const unsigned short* __restrict__ K,
    const unsigned short* __restrict__ Vt, unsigned short* __restrict__ O) {
  __shared__ __align__(16) unsigned short Vs[4][64 * 64];  // wave-private, swizzled [dv][kv]
  __shared__ __align__(16) unsigned short Pl[4][32 * 68];  // wave-private P relayout
  const int L = blockIdx.x + 16 * blockIdx.y;
  const int rr = L & 31;
  const int bh = (rr & 7) * 4 + (rr >> 3);
  const int a = L >> 5;
  const int qt = (a < 8) ? a : 23 - a;
  const int tid = threadIdx.x, lane = tid & 63, w = tid >> 6;
  const int lr = lane & 15, lg = lane >> 4;
  const unsigned short* Qg = Q + (size_t)bh * 2048 * 64;
  const unsigned short* Kg = K + (size_t)bh * 2048 * 64;
  const unsigned short* Vg = Vt + (size_t)bh * 64 * 2048;
  const int qrow = qt * 128 + w * 32;
  const int Tw = (qrow + 95) >> 6;  // tiles this wave actually needs
  unsigned short* Vw = &Vs[w][0];
  unsigned short* Pw = &Pl[w][0];

  // Q fragments: 32 rows x 64 d per wave
  bf16x8 qf[2][2];
#pragma unroll
  for (int mi = 0; mi < 2; ++mi)
#pragma unroll
    for (int h = 0; h < 2; ++h)
      qf[mi][h] = *(const bf16x8*)(Qg + (qrow + mi * 16 + lr) * 64 + h * 32 + lg * 8);

  // ones B-fragment (for row-sum via MFMA)
  u16x8 ouv;
#pragma unroll
  for (int j = 0; j < 8; ++j) ouv[j] = 0x3F80;  // bf16 1.0
  const bf16x8 onesf = __builtin_bit_cast(bf16x8, ouv);

  f32x4 oacc[2][4] = {};
  float mrow[2][4], lrow[2][4];
#pragma unroll
  for (int mi = 0; mi < 2; ++mi)
#pragma unroll
    for (int r = 0; r < 4; ++r) { mrow[mi][r] = -__builtin_inff(); lrow[mi][r] = 0.f; }

  const float SCL = 0.125f * 1.44269504088896f;  // 1/sqrt(64) * log2(e)

  // V staging: 8 load_lds per wave; instr i writes LDS row r=i*8+(lane>>3),
  // slot j=lane&7 from global col-chunk j^(r&7) (XOR swizzle via source).
  auto issueV = [&](int kv0) {
#pragma unroll
    for (int i = 0; i < 8; ++i) {
      const int r = i * 8 + (lane >> 3);
      const int j = lane & 7;
      load_lds16(Vg + (size_t)r * 2048 + kv0 + ((j ^ (r & 7)) * 8),
                 Vw + i * 512 + lane * 8);
    }
  };
  // K fragments straight from global (per-lane 16B, rows L2/L1-resident)
  auto loadK = [&](bf16x8 (&kd)[4][2], int kv0) {
#pragma unroll
    for (int nt = 0; nt < 4; ++nt)
#pragma unroll
      for (int h = 0; h < 2; ++h)
        kd[nt][h] = *(const bf16x8*)(Kg + (size_t)(kv0 + nt * 16 + lr) * 64 +
                                     h * 32 + lg * 8);
  };

  bf16x8 kA[4][2], kB[4][2];
  loadK(kA, 0);
  issueV(0);

  auto body = [&](int t, bf16x8 (&kc)[4][2], bf16x8 (&kn)[4][2]) {
    const int kv0 = t * 64;
    const bool more = (t + 1 < Tw);
    if (more) loadK(kn, kv0 + 64);  // next K tile in flight during this tile

    // ---- S = Q K^T : 32 q x 64 kv (raw scores) ----
    f32x4 sacc[2][4];
    __builtin_amdgcn_s_setprio(1);
#pragma unroll
    for (int nt = 0; nt < 4; ++nt) {
#pragma unroll
      for (int mi = 0; mi < 2; ++mi) {
        f32x4 z = {0.f, 0.f, 0.f, 0.f};
        z = __builtin_amdgcn_mfma_f32_16x16x32_bf16(qf[mi][0], kc[nt][0], z, 0, 0, 0);
        sacc[mi][nt] = __builtin_amdgcn_mfma_f32_16x16x32_bf16(qf[mi][1], kc[nt][1], z, 0, 0, 0);
      }
    }
    __builtin_amdgcn_s_setprio(0);

    // ---- causal mask (raw domain) + row max ----
    const bool needmask = (t == Tw - 1);  // wave-uniform: only last tile partial
    float pm[2][4];
#pragma unroll
    for (int mi = 0; mi < 2; ++mi)
#pragma unroll
      for (int r = 0; r < 4; ++r) pm[mi][r] = -__builtin_inff();
#pragma unroll
    for (int mi = 0; mi < 2; ++mi)
#pragma unroll
      for (int nt = 0; nt < 4; ++nt)
#pragma unroll
        for (int reg = 0; reg < 4; ++reg) {
          float sv = sacc[mi][nt][reg];
          if (needmask) {
            const int kg = kv0 + nt * 16 + lr;
            const int qg = qrow + mi * 16 + lg * 4 + reg;
            if (kg > qg) sv = -__builtin_inff();
          }
          sacc[mi][nt][reg] = sv;
          pm[mi][reg] = fmaxf(pm[mi][reg], sv);
        }
#pragma unroll
    for (int off = 1; off < 16; off <<= 1)
#pragma unroll
      for (int mi = 0; mi < 2; ++mi)
#pragma unroll
        for (int reg = 0; reg < 4; ++reg)
          pm[mi][reg] = fmaxf(pm[mi][reg], __shfl_xor(pm[mi][reg], off));

    // ---- online softmax (exp2 domain, deferred rescale when max didn't grow) ----
    float gm = -1.f;
#pragma unroll
    for (int mi = 0; mi < 2; ++mi)
#pragma unroll
      for (int reg = 0; reg < 4; ++reg)
        gm = fmaxf(gm, pm[mi][reg] - mrow[mi][reg]);
    float al[2][4], msc[2][4];
    if (__any(gm > 0.f)) {
#pragma unroll
      for (int mi = 0; mi < 2; ++mi)
#pragma unroll
        for (int reg = 0; reg < 4; ++reg) {
          const float mn = fmaxf(mrow[mi][reg], pm[mi][reg]);
          al[mi][reg] = exp2f(SCL * (mrow[mi][reg] - mn));
          mrow[mi][reg] = mn;
          msc[mi][reg] = SCL * mn;
#pragma unroll
          for (int nt = 0; nt < 4; ++nt) oacc[mi][nt][reg] *= al[mi][reg];
          lrow[mi][reg] *= al[mi][reg];
        }
    } else {
#pragma unroll
      for (int mi = 0; mi < 2; ++mi)
#pragma unroll
        for (int reg = 0; reg < 4; ++reg) msc[mi][reg] = SCL * mrow[mi][reg];
    }
#pragma unroll
    for (int mi = 0; mi < 2; ++mi)
#pragma unroll
      for (int nt = 0; nt < 4; ++nt)
#pragma unroll
        for (int reg = 0; reg < 4; ++reg)
          sacc[mi][nt][reg] = exp2f(sacc[mi][nt][reg] * SCL - msc[mi][reg]);

    // ---- P relayout through padded wave-local LDS ----
#pragma unroll
    for (int mi = 0; mi < 2; ++mi)
#pragma unroll
      for (int nt = 0; nt < 4; ++nt)
#pragma unroll
        for (int reg = 0; reg < 4; ++reg)
          Pw[(mi * 16 + lg * 4 + reg) * 68 + nt * 16 + lr] =
              f2bf(sacc[mi][nt][reg]);
    bf16x8 pa[2][2];
#pragma unroll
    for (int mi = 0; mi < 2; ++mi)
#pragma unroll
      for (int ks = 0; ks < 2; ++ks)
        pa[mi][ks] = *(const bf16x8*)(Pw + (mi * 16 + lr) * 68 + ks * 32 + lg * 8);

    // ---- wait for this tile's V (counted: next-K stays in flight) ----
    if (more) asm volatile("s_waitcnt vmcnt(8)" ::: "memory");
    else      asm volatile("s_waitcnt vmcnt(0)" ::: "memory");

    // ---- row-sum via ones-MFMA + O += P V ----
    __builtin_amdgcn_s_setprio(1);
#pragma unroll
    for (int mi = 0; mi < 2; ++mi) {
      f32x4 z = {0.f, 0.f, 0.f, 0.f};
      z = __builtin_amdgcn_mfma_f32_16x16x32_bf16(pa[mi][0], onesf, z, 0, 0, 0);
      z = __builtin_amdgcn_mfma_f32_16x16x32_bf16(pa[mi][1], onesf, z, 0, 0, 0);
#pragma unroll
      for (int reg = 0; reg < 4; ++reg) lrow[mi][reg] += z[reg];
    }
#pragma unroll
    for (int nt = 0; nt < 4; ++nt) {
      const int row = nt * 16 + lr;
      const bf16x8 vb0 = *(const bf16x8*)(Vw + row * 64 + ((lg ^ (row & 7)) * 8));
      const bf16x8 vb1 = *(const bf16x8*)(Vw + row * 64 + (((lg + 4) ^ (row & 7)) * 8));
#pragma unroll
      for (int mi = 0; mi < 2; ++mi) {
        oacc[mi][nt] = __builtin_amdgcn_mfma_f32_16x16x32_bf16(pa[mi][0], vb0,
                                                               oacc[mi][nt], 0, 0, 0);
        oacc[mi][nt] = __builtin_amdgcn_mfma_f32_16x16x32_bf16(pa[mi][1], vb1,
                                                               oacc[mi][nt], 0, 0, 0);
      }
    }
    __builtin_amdgcn_s_setprio(0);

    // ensure this tile's V reads are fully done before overwriting the buffer
    asm volatile("s_waitcnt lgkmcnt(0)" ::: "memory");
    if (more) issueV(kv0 + 64);  // V(t+1) flies during next tile's QKT+softmax
  };

  int t = 0;
  while (t < Tw) {
    body(t, kA, kB); ++t;
    if (t < Tw) { body(t, kB, kA); ++t; }
  }

  // ---- normalize + write attn out as bf16 [B][S][H*64] ----
  const int b = bh >> 4, h = bh & 15;
#pragma unroll
  for (int mi = 0; mi < 2; ++mi)
#pragma unroll
    for (int reg = 0; reg < 4; ++reg) {
      const float inv = 1.0f / lrow[mi][reg];
      const int s = qrow + mi * 16 + lg * 4 + reg;
#pragma unroll
      for (int nt = 0; nt < 4; ++nt) {
        const int dv = nt * 16 + lr;
        O[((size_t)b * 2048 + s) * 1024 + h * 64 + dv] = f2bf(oacc[mi][nt][reg] * inv);
      }
    }
}

// ---------- stage 3: output projection, f32 epilogue ----------
__global__ __launch_bounds__(256) void k_out(const unsigned short* __restrict__ Ab,
                                             const unsigned short* __restrict__ Wo,
                                             float* __restrict__ Out) {
  __shared__ __align__(16) unsigned short As[3 * 128 * 32];
  __shared__ __align__(16) unsigned short Bs[3 * 128 * 32];
  const int tid = threadIdx.x;
  const int bm = blockIdx.x * 128, bn = blockIdx.y * 128;
  f32x4 acc[4][4] = {};
  gemm_core_1024(Ab + (size_t)bm * 1024, Wo + (size_t)bn * 1024, As, Bs, acc, tid);
  const int lane = tid & 63, w = tid >> 6;
  const int wm = (w >> 1) * 64, wn = (w & 1) * 64;
  const int lr = lane & 15, lg = lane >> 4;
#pragma unroll
  for (int mi = 0; mi < 4; ++mi)
#pragma unroll
    for (int ni = 0; ni < 4; ++ni)
#pragma unroll
      for (int reg = 0; reg < 4; ++reg) {
        const int r = bm + wm + mi * 16 + lg * 4 + reg;
        const int e = bn + wn + ni * 16 + lr;
        Out[(size_t)r * 1024 + e] = acc[mi][ni][reg];
      }
}

// ---------- launch ----------
extern "C" void kernel_launch(void* const* d_in, const int* in_sizes, int n_in,
                              void* d_out, int out_size, void* d_ws, size_t ws_size,
                              hipStream_t stream) {
  const float* x = (const float*)d_in[0];
  const float* Wq = (const float*)d_in[1];
  const float* Wk = (const float*)d_in[2];
  const float* Wv = (const float*)d_in[3];
  const float* Wo = (const float*)d_in[4];
  const int* tpos = (const int*)d_in[5];
  float* out = (float*)d_out;
  char* ws = (char*)d_ws;
  const size_t MB = 1024 * 1024;
  unsigned short* xb = (unsigned short*)(ws);             // 8 MB
  unsigned short* wqb = (unsigned short*)(ws + 8 * MB);   // 2 MB
  unsigned short* wkb = (unsigned short*)(ws + 10 * MB);
  unsigned short* wvb = (unsigned short*)(ws + 12 * MB);
  unsigned short* wob = (unsigned short*)(ws + 14 * MB);
  unsigned short* Qb = (unsigned short*)(ws + 16 * MB);   // 8 MB each
  unsigned short* Kb = (unsigned short*)(ws + 24 * MB);
  unsigned short* Vtb = (unsigned short*)(ws + 32 * MB);  // transposed V
  unsigned short* Ab = (unsigned short*)(ws + 40 * MB);
  float* ctab = (float*)(ws + 48 * MB);                   // 256 KB
  float* stab = (float*)(ws + 48 * MB + 256 * 1024);

  k_convert<<<dim3(8192), dim3(256), 0, stream>>>(x, Wq, Wk, Wv, Wo, xb, wqb, wkb,
                                                  wvb, wob);
  k_rope_tab<<<dim3(256), dim3(256), 0, stream>>>(tpos, ctab, stab);
  k_proj<<<dim3(32, 8, 3), dim3(256), 0, stream>>>(xb, wqb, wkb, wvb, ctab, stab,
                                                   Qb, Kb, Vtb);
  k_attn<<<dim3(16, 32), dim3(256), 0, stream>>>(Qb, Kb, Vtb, Ab);
  k_out<<<dim3(32, 8), dim3(256), 0, stream>>>(Ab, wob, out);
}

// Round 6
// 158.649 us; speedup vs baseline: 2.1819x; 1.1664x over previous
//
#include <hip/hip_runtime.h>

typedef __bf16 bf16x8 __attribute__((ext_vector_type(8)));
typedef float f32x4 __attribute__((ext_vector_type(4)));
typedef unsigned short u16x8 __attribute__((ext_vector_type(8)));

// ---------- helpers ----------

__device__ __forceinline__ unsigned short f2bf(float f) {
  unsigned u = __builtin_bit_cast(unsigned, f);
  u = (u + 0x7FFFu + ((u >> 16) & 1u)) >> 16;   // RNE
  return (unsigned short)u;
}

__device__ __forceinline__ void load_lds16(const void* g, void* l) {
  __builtin_amdgcn_global_load_lds(
      (__attribute__((address_space(1))) void*)g,
      (__attribute__((address_space(3))) void*)l, 16, 0, 0);
}

// ---------- stage 0: dtype convert ----------
__global__ __launch_bounds__(256) void k_convert(
    const float* __restrict__ x,
    const float* __restrict__ wq, const float* __restrict__ wk,
    const float* __restrict__ wv, const float* __restrict__ wo,
    unsigned short* __restrict__ xb,
    unsigned short* __restrict__ wqb, unsigned short* __restrict__ wkb,
    unsigned short* __restrict__ wvb, unsigned short* __restrict__ wob) {
  const int g = blockIdx.x * 256 + threadIdx.x;  // exactly 2M threads
  const float* src;
  unsigned short* dst;
  int off;
  if (g < (1 << 20)) {
    src = x; dst = xb; off = g;
  } else {
    const int q = g - (1 << 20);
    const int t = q >> 18;
    off = q & ((1 << 18) - 1);
    src = (t == 0) ? wq : (t == 1) ? wk : (t == 2) ? wv : wo;
    dst = (t == 0) ? wqb : (t == 1) ? wkb : (t == 2) ? wvb : wob;
  }
  const float4 v = ((const float4*)src)[off];
  ushort4 r;
  r.x = f2bf(v.x); r.y = f2bf(v.y); r.z = f2bf(v.z); r.w = f2bf(v.w);
  ((ushort4*)dst)[off] = r;
}

// ---------- stage 0b: rope table ----------
__global__ __launch_bounds__(256) void k_rope_tab(const int* __restrict__ tpos,
                                                  float* __restrict__ ct,
                                                  float* __restrict__ st) {
  const int idx = blockIdx.x * 256 + threadIdx.x;  // 2048*32 = 64K
  const int s = idx >> 5, i = idx & 31;
  const double p = (double)tpos[s];
  const double f = p * pow(10000.0, -(double)(2 * i) / 64.0);
  ct[idx] = (float)cos(f);
  st[idx] = (float)sin(f);
}

// ---------- GEMM core: C[128x128] += A[128xK] * B[128xK]^T, K=1024, BK=32 ----------
// 3-deep staging pipeline with counted vmcnt. As/Bs are 3*128*32 elems.
__device__ __forceinline__ void gemm_core_1024(
    const unsigned short* __restrict__ Ag,  // at row bm
    const unsigned short* __restrict__ Bg,  // at row bn
    unsigned short* As, unsigned short* Bs, f32x4 (&acc)[4][4], int tid) {
  const int lane = tid & 63;
  const int w = tid >> 6;
  const int wm = (w >> 1) * 64;
  const int wn = (w & 1) * 64;
  const int lr = lane & 15;
  const int lg8 = (lane >> 4) * 8;
  const int c0 = tid, c1 = 256 + tid;
  const int ar0 = c0 >> 2, ac0 = (c0 & 3) * 8;
  const int ar1 = c1 >> 2, ac1 = (c1 & 3) * 8;

  auto stage = [&](int buf, int kt) {
    unsigned short* Ab = As + buf * 4096;
    unsigned short* Bb = Bs + buf * 4096;
    load_lds16(Ag + ar0 * 1024 + kt + ac0, Ab + c0 * 8);
    load_lds16(Ag + ar1 * 1024 + kt + ac1, Ab + c1 * 8);
    load_lds16(Bg + ar0 * 1024 + kt + ac0, Bb + c0 * 8);
    load_lds16(Bg + ar1 * 1024 + kt + ac1, Bb + c1 * 8);
  };

  stage(0, 0);
  stage(1, 32);
  int cur = 0;
  for (int ki = 0; ki < 32; ++ki) {
    if (ki + 2 < 32) {
      int nb = cur + 2; if (nb >= 3) nb -= 3;
      stage(nb, (ki + 2) * 32);
      asm volatile("s_waitcnt vmcnt(8)" ::: "memory");
    } else if (ki + 1 < 32) {
      asm volatile("s_waitcnt vmcnt(4)" ::: "memory");
    } else {
      asm volatile("s_waitcnt vmcnt(0)" ::: "memory");
    }
    __builtin_amdgcn_s_barrier();
    const unsigned short* Ab = As + cur * 4096;
    const unsigned short* Bb = Bs + cur * 4096;
    bf16x8 af[4], bfv[4];
#pragma unroll
    for (int mi = 0; mi < 4; ++mi)
      af[mi] = *(const bf16x8*)(Ab + (wm + mi * 16 + lr) * 32 + lg8);
#pragma unroll
    for (int ni = 0; ni < 4; ++ni)
      bfv[ni] = *(const bf16x8*)(Bb + (wn + ni * 16 + lr) * 32 + lg8);
    __builtin_amdgcn_s_setprio(1);
#pragma unroll
    for (int mi = 0; mi < 4; ++mi)
#pragma unroll
      for (int ni = 0; ni < 4; ++ni)
        acc[mi][ni] = __builtin_amdgcn_mfma_f32_16x16x32_bf16(
            af[mi], bfv[ni], acc[mi][ni], 0, 0, 0);
    __builtin_amdgcn_s_setprio(0);
    __builtin_amdgcn_s_barrier();
    ++cur; if (cur == 3) cur = 0;
  }
}

// ---------- stage 1: q/k/v projection + rope ----------
// Q,K out: bf16 [B*H][S][64]. V out: TRANSPOSED bf16 [B*H][64][S] (for attn staging).
__global__ __launch_bounds__(256) void k_proj(
    const unsigned short* __restrict__ Xb,
    const unsigned short* __restrict__ Wq, const unsigned short* __restrict__ Wk,
    const unsigned short* __restrict__ Wv,
    const float* __restrict__ ctab, const float* __restrict__ stab,
    unsigned short* __restrict__ Qo, unsigned short* __restrict__ Ko,
    unsigned short* __restrict__ Vo) {
  __shared__ __align__(16) unsigned short As[3 * 128 * 32];
  __shared__ __align__(16) unsigned short Bs[3 * 128 * 32];
  const int z = blockIdx.z;
  const unsigned short* Wsel = (z == 0) ? Wq : (z == 1) ? Wk : Wv;
  unsigned short* Out = (z == 0) ? Qo : (z == 1) ? Ko : Vo;
  const int tid = threadIdx.x;
  const int bm = blockIdx.x * 128, bn = blockIdx.y * 128;
  f32x4 acc[4][4] = {};
  gemm_core_1024(Xb + (size_t)bm * 1024, Wsel + (size_t)bn * 1024, As, Bs, acc, tid);

  const int lane = tid & 63, w = tid >> 6;
  const int wm = (w >> 1) * 64, wn = (w & 1) * 64;
  const int lr = lane & 15, lg = lane >> 4;
  const bool rope = (z < 2);
  const bool odd = lane & 1;
#pragma unroll
  for (int mi = 0; mi < 4; ++mi) {
#pragma unroll
    for (int ni = 0; ni < 4; ++ni) {
#pragma unroll
      for (int reg = 0; reg < 4; ++reg) {
        const int r = bm + wm + mi * 16 + lg * 4 + reg;  // D row -> (b,s)
        const int e = bn + wn + ni * 16 + lr;            // D col -> (h,d)
        float val = acc[mi][ni][reg];
        const float partner = __shfl_xor(val, 1);
        const int s = r & 2047, b = r >> 11;
        const int h = e >> 6, d = e & 63;
        float outv = val;
        if (rope) {
          const int i = d >> 1;
          const float c = ctab[s * 32 + i];
          const float sn = stab[s * 32 + i];
          outv = odd ? (val * c + partner * sn) : (val * c - partner * sn);
        }
        if (z == 2)
          Out[((size_t)(b * 16 + h) * 64 + d) * 2048 + s] = f2bf(outv);
        else
          Out[((size_t)(b * 16 + h) * 2048 + s) * 64 + d] = f2bf(outv);
      }
    }
  }
}

// ---------- stage 2: causal flash attention, single-wave blocks, paired strips ----------
// 2048 blocks of 64 threads. Block L: xcd=L&7, i=L>>3, bh=xcd*4+(i&3), p=i>>2.
// Wave owns TWO 16-row q-strips: sA=p (light), sB=127-p (heavy), processed
// concurrently over one shared KV stream -> every wave does ~34 strip-tiles of
// compute (uniform). K double-buffered in regs, V in wave-private LDS. No barriers.
__global__ __launch_bounds__(64, 2) void k_attn(
    const unsigned short* __restrict__ Q, const unsigned short* __restrict__ K,
    const unsigned short* __restrict__ Vt, unsigned short* __restrict__ O) {
  __shared__ __align__(16) unsigned short Vs[64 * 64];   // swizzled [dv][kv]
  __shared__ __align__(16) unsigned short Pl[32 * 68];   // rows 0-15 A, 16-31 B
  const int L = blockIdx.x;
  const int bh = (L & 7) * 4 + ((L >> 3) & 3);
  const int p = L >> 5;                 // 0..63
  const int qrowA = p * 16, qrowB = (127 - p) * 16;
  const int lane = threadIdx.x & 63;
  const int lr = lane & 15, lg = lane >> 4;
  const unsigned short* Qg = Q + (size_t)bh * 2048 * 64;
  const unsigned short* Kg = K + (size_t)bh * 2048 * 64;
  const unsigned short* Vg = Vt + (size_t)bh * 64 * 2048;
  const int Ta = (qrowA + 79) >> 6;
  const int Tb = (qrowB + 79) >> 6;

  // Q fragments: 16 rows x 64 d per strip
  bf16x8 qfA[2], qfB[2];
#pragma unroll
  for (int h = 0; h < 2; ++h) {
    qfA[h] = *(const bf16x8*)(Qg + (qrowA + lr) * 64 + h * 32 + lg * 8);
    qfB[h] = *(const bf16x8*)(Qg + (qrowB + lr) * 64 + h * 32 + lg * 8);
  }

  // ones B-fragment (for row-sum via MFMA)
  u16x8 ouv;
#pragma unroll
  for (int j = 0; j < 8; ++j) ouv[j] = 0x3F80;  // bf16 1.0
  const bf16x8 onesf = __builtin_bit_cast(bf16x8, ouv);

  f32x4 oA[4] = {}, oB[4] = {};
  float mA[4], lA[4], mB[4], lB[4];
#pragma unroll
  for (int r = 0; r < 4; ++r) {
    mA[r] = -__builtin_inff(); lA[r] = 0.f;
    mB[r] = -__builtin_inff(); lB[r] = 0.f;
  }

  const float SCL = 0.125f * 1.44269504088896f;  // 1/sqrt(64) * log2(e)

  // advancing-pointer staging (strength-reduced addressing)
  const int kbase = lr * 64 + lg * 8;
  const unsigned short* Knext = Kg;                 // advances 4096/tile
  const int vbase = (lane >> 3) * 2048 + (((lane & 7) ^ (lane >> 3)) * 8);
  const unsigned short* Vnext = Vg;                 // advances 64/tile
  unsigned short* Vw = &Vs[0];

  auto loadK = [&](bf16x8 (&kd)[4][2]) {
#pragma unroll
    for (int nt = 0; nt < 4; ++nt)
#pragma unroll
      for (int h = 0; h < 2; ++h)
        kd[nt][h] = *(const bf16x8*)(Knext + nt * 1024 + h * 32 + kbase);
    Knext += 4096;
  };
  auto issueV = [&]() {
#pragma unroll
    for (int i0 = 0; i0 < 8; ++i0)
      load_lds16(Vnext + i0 * 16384 + vbase, Vw + i0 * 512 + lane * 8);
    Vnext += 64;
  };

  // per-strip softmax + P-relayout (exp2 domain, deferred rescale)
  auto softmax = [&](f32x4 (&s)[4], float (&m)[4], float (&l)[4], f32x4 (&oa)[4],
                     int qrow, bool needmask, int kv0, int rowbase) {
    float pm[4];
#pragma unroll
    for (int r = 0; r < 4; ++r) pm[r] = -__builtin_inff();
#pragma unroll
    for (int nt = 0; nt < 4; ++nt)
#pragma unroll
      for (int reg = 0; reg < 4; ++reg) {
        float sv = s[nt][reg];
        if (needmask) {
          const int kg = kv0 + nt * 16 + lr;
          const int qg = qrow + lg * 4 + reg;
          if (kg > qg) sv = -__builtin_inff();
        }
        s[nt][reg] = sv;
        pm[reg] = fmaxf(pm[reg], sv);
      }
#pragma unroll
    for (int off = 1; off < 16; off <<= 1)
#pragma unroll
      for (int reg = 0; reg < 4; ++reg)
        pm[reg] = fmaxf(pm[reg], __shfl_xor(pm[reg], off));

    float gm = -1.f;
#pragma unroll
    for (int reg = 0; reg < 4; ++reg) gm = fmaxf(gm, pm[reg] - m[reg]);
    float msc[4];
    if (__any(gm > 0.f)) {
#pragma unroll
      for (int reg = 0; reg < 4; ++reg) {
        const float mn = fmaxf(m[reg], pm[reg]);
        const float al = exp2f(SCL * (m[reg] - mn));
        m[reg] = mn;
        msc[reg] = SCL * mn;
        l[reg] *= al;
#pragma unroll
        for (int nt = 0; nt < 4; ++nt) oa[nt][reg] *= al;
      }
    } else {
#pragma unroll
      for (int reg = 0; reg < 4; ++reg) msc[reg] = SCL * m[reg];
    }
#pragma unroll
    for (int nt = 0; nt < 4; ++nt)
#pragma unroll
      for (int reg = 0; reg < 4; ++reg) {
        const float pv = exp2f(s[nt][reg] * SCL - msc[reg]);
        Pl[(rowbase + lg * 4 + reg) * 68 + nt * 16 + lr] = f2bf(pv);
      }
  };

  bf16x8 kA_[4][2], kB_[4][2];
  loadK(kA_);
  issueV();

  auto body = [&](int t, bf16x8 (&kc)[4][2], bf16x8 (&kn)[4][2]) {
    const int kv0 = t * 64;
    const bool more = (t + 1 < Tb);
    const bool actA = (t < Ta);
    if (more) loadK(kn);  // next K tile in flight during this tile

    // ---- S = Q K^T (raw scores) ----
    f32x4 sB_[4];
    __builtin_amdgcn_s_setprio(1);
#pragma unroll
    for (int nt = 0; nt < 4; ++nt) {
      f32x4 z = {0.f, 0.f, 0.f, 0.f};
      z = __builtin_amdgcn_mfma_f32_16x16x32_bf16(qfB[0], kc[nt][0], z, 0, 0, 0);
      sB_[nt] = __builtin_amdgcn_mfma_f32_16x16x32_bf16(qfB[1], kc[nt][1], z, 0, 0, 0);
    }
    __builtin_amdgcn_s_setprio(0);
    softmax(sB_, mB, lB, oB, qrowB, t == Tb - 1, kv0, 16);

    if (actA) {
      f32x4 sA_[4];
      __builtin_amdgcn_s_setprio(1);
#pragma unroll
      for (int nt = 0; nt < 4; ++nt) {
        f32x4 z = {0.f, 0.f, 0.f, 0.f};
        z = __builtin_amdgcn_mfma_f32_16x16x32_bf16(qfA[0], kc[nt][0], z, 0, 0, 0);
        sA_[nt] = __builtin_amdgcn_mfma_f32_16x16x32_bf16(qfA[1], kc[nt][1], z, 0, 0, 0);
      }
      __builtin_amdgcn_s_setprio(0);
      softmax(sA_, mA, lA, oA, qrowA, t == Ta - 1, kv0, 0);
    }

    // ---- A-fragments of P ----
    bf16x8 paA[2], paB[2];
#pragma unroll
    for (int ks = 0; ks < 2; ++ks) {
      paB[ks] = *(const bf16x8*)(Pl + (16 + lr) * 68 + ks * 32 + lg * 8);
      if (actA) paA[ks] = *(const bf16x8*)(Pl + lr * 68 + ks * 32 + lg * 8);
    }

    // ---- wait for this tile's V (counted: next-K stays in flight) ----
    if (more) asm volatile("s_waitcnt vmcnt(8)" ::: "memory");
    else      asm volatile("s_waitcnt vmcnt(0)" ::: "memory");

    // ---- row-sums + O += P V ----
    __builtin_amdgcn_s_setprio(1);
    {
      f32x4 z = {0.f, 0.f, 0.f, 0.f};
      z = __builtin_amdgcn_mfma_f32_16x16x32_bf16(paB[0], onesf, z, 0, 0, 0);
      z = __builtin_amdgcn_mfma_f32_16x16x32_bf16(paB[1], onesf, z, 0, 0, 0);
#pragma unroll
      for (int reg = 0; reg < 4; ++reg) lB[reg] += z[reg];
    }
    if (actA) {
      f32x4 z = {0.f, 0.f, 0.f, 0.f};
      z = __builtin_amdgcn_mfma_f32_16x16x32_bf16(paA[0], onesf, z, 0, 0, 0);
      z = __builtin_amdgcn_mfma_f32_16x16x32_bf16(paA[1], onesf, z, 0, 0, 0);
#pragma unroll
      for (int reg = 0; reg < 4; ++reg) lA[reg] += z[reg];
    }
#pragma unroll
    for (int nt = 0; nt < 4; ++nt) {
      const int row = nt * 16 + lr;
      const bf16x8 vb0 = *(const bf16x8*)(Vw + row * 64 + ((lg ^ (row & 7)) * 8));
      const bf16x8 vb1 = *(const bf16x8*)(Vw + row * 64 + (((lg + 4) ^ (row & 7)) * 8));
      oB[nt] = __builtin_amdgcn_mfma_f32_16x16x32_bf16(paB[0], vb0, oB[nt], 0, 0, 0);
      oB[nt] = __builtin_amdgcn_mfma_f32_16x16x32_bf16(paB[1], vb1, oB[nt], 0, 0, 0);
      if (actA) {
        oA[nt] = __builtin_amdgcn_mfma_f32_16x16x32_bf16(paA[0], vb0, oA[nt], 0, 0, 0);
        oA[nt] = __builtin_amdgcn_mfma_f32_16x16x32_bf16(paA[1], vb1, oA[nt], 0, 0, 0);
      }
    }
    __builtin_amdgcn_s_setprio(0);

    // V buffer reads fully retired before next-tile DMA overwrites it
    asm volatile("s_waitcnt lgkmcnt(0)" ::: "memory");
    if (more) issueV();
  };

  int t = 0;
  for (;;) {
    body(t, kA_, kB_); ++t; if (t >= Tb) break;
    body(t, kB_, kA_); ++t; if (t >= Tb) break;
  }

  // ---- normalize + write attn out as bf16 [B][S][H*64] ----
  const int b = bh >> 4, h = bh & 15;
#pragma unroll
  for (int reg = 0; reg < 4; ++reg) {
    const float invA = 1.0f / lA[reg];
    const float invB = 1.0f / lB[reg];
    const int sA_ = qrowA + lg * 4 + reg;
    const int sB_ = qrowB + lg * 4 + reg;
#pragma unroll
    for (int nt = 0; nt < 4; ++nt) {
      const int dv = nt * 16 + lr;
      O[((size_t)b * 2048 + sA_) * 1024 + h * 64 + dv] = f2bf(oA[nt][reg] * invA);
      O[((size_t)b * 2048 + sB_) * 1024 + h * 64 + dv] = f2bf(oB[nt][reg] * invB);
    }
  }
}

// ---------- stage 3: output projection, f32 epilogue ----------
__global__ __launch_bounds__(256) void k_out(const unsigned short* __restrict__ Ab,
                                             const unsigned short* __restrict__ Wo,
                                             float* __restrict__ Out) {
  __shared__ __align__(16) unsigned short As[3 * 128 * 32];
  __shared__ __align__(16) unsigned short Bs[3 * 128 * 32];
  const int tid = threadIdx.x;
  const int bm = blockIdx.x * 128, bn = blockIdx.y * 128;
  f32x4 acc[4][4] = {};
  gemm_core_1024(Ab + (size_t)bm * 1024, Wo + (size_t)bn * 1024, As, Bs, acc, tid);
  const int lane = tid & 63, w = tid >> 6;
  const int wm = (w >> 1) * 64, wn = (w & 1) * 64;
  const int lr = lane & 15, lg = lane >> 4;
#pragma unroll
  for (int mi = 0; mi < 4; ++mi)
#pragma unroll
    for (int ni = 0; ni < 4; ++ni)
#pragma unroll
      for (int reg = 0; reg < 4; ++reg) {
        const int r = bm + wm + mi * 16 + lg * 4 + reg;
        const int e = bn + wn + ni * 16 + lr;
        Out[(size_t)r * 1024 + e] = acc[mi][ni][reg];
      }
}

// ---------- launch ----------
extern "C" void kernel_launch(void* const* d_in, const int* in_sizes, int n_in,
                              void* d_out, int out_size, void* d_ws, size_t ws_size,
                              hipStream_t stream) {
  const float* x = (const float*)d_in[0];
  const float* Wq = (const float*)d_in[1];
  const float* Wk = (const float*)d_in[2];
  const float* Wv = (const float*)d_in[3];
  const float* Wo = (const float*)d_in[4];
  const int* tpos = (const int*)d_in[5];
  float* out = (float*)d_out;
  char* ws = (char*)d_ws;
  const size_t MB = 1024 * 1024;
  unsigned short* xb = (unsigned short*)(ws);             // 8 MB
  unsigned short* wqb = (unsigned short*)(ws + 8 * MB);   // 2 MB
  unsigned short* wkb = (unsigned short*)(ws + 10 * MB);
  unsigned short* wvb = (unsigned short*)(ws + 12 * MB);
  unsigned short* wob = (unsigned short*)(ws + 14 * MB);
  unsigned short* Qb = (unsigned short*)(ws + 16 * MB);   // 8 MB each
  unsigned short* Kb = (unsigned short*)(ws + 24 * MB);
  unsigned short* Vtb = (unsigned short*)(ws + 32 * MB);  // transposed V
  unsigned short* Ab = (unsigned short*)(ws + 40 * MB);
  float* ctab = (float*)(ws + 48 * MB);                   // 256 KB
  float* stab = (float*)(ws + 48 * MB + 256 * 1024);

  k_convert<<<dim3(8192), dim3(256), 0, stream>>>(x, Wq, Wk, Wv, Wo, xb, wqb, wkb,
                                                  wvb, wob);
  k_rope_tab<<<dim3(256), dim3(256), 0, stream>>>(tpos, ctab, stab);
  k_proj<<<dim3(32, 8, 3), dim3(256), 0, stream>>>(xb, wqb, wkb, wvb, ctab, stab,
                                                   Qb, Kb, Vtb);
  k_attn<<<dim3(2048), dim3(64), 0, stream>>>(Qb, Kb, Vtb, Ab);
  k_out<<<dim3(32, 8), dim3(256), 0, stream>>>(Ab, wob, out);
}